// Round 7
// baseline (173.574 us; speedup 1.0000x reference)
//
#include <hip/hip_runtime.h>
#include <math.h>

#define N_PATHS 23
#define HIDDEN  32
#define N_NODES 4096
#define N_EDGES 8192
#define FEAT    512
#define BLK     128   // 2 waves; 4 edges per wave (R11 structure; R18 LDS diet -> 8 blocks/CU)
#define ZERO_BLOCKS 256

// wave-local LDS phase separator (all prior DS ops complete)
#define WAVE_SYNC() asm volatile("s_waitcnt lgkmcnt(0)" ::: "memory")

typedef __attribute__((ext_vector_type(8)))  short bf16x8;
typedef __attribute__((ext_vector_type(16))) float f32x16;

// ---- compile-time path metadata (PATHS enumeration: l1 outer, l2, l3) ----
constexpr int cL1[N_PATHS] = {0,0,0,0, 1,1,1,1,1,1, 2,2,2,2,2,2,2, 3,3,3,3,3,3};
constexpr int cL2[N_PATHS] = {0,1,2,3, 0,1,1,2,2,3, 0,1,1,2,2,3,3, 0,1,2,2,3,3};
constexpr int cCOFF[N_PATHS]= {0,1,10,35,84,93,102,147,192,297,402,427,472,577,602,727,832,1077,1126,1231,1336,1581,1630};
constexpr int cL3P[N_PATHS] = {0,5,13,21, 1,4,7,11,15,19, 2,6,9,10,14,18,22, 3,8,12,16,17,20};
constexpr int cL3S[5] = {0,4,10,17,23};
constexpr int cOFF3[4] = {0,32,128,288};
__device__ const int CNT_L3[4] = {4,6,7,6};
__device__ const int D_L3[N_PATHS] = {0,1,2,3, 1,0,2,1,3,2, 2,1,3,0,2,1,3, 3,2,1,3,0,2};

// per-edge z offset of path slot pi within its group's batched z buffer
constexpr int zOff(int G, int pi) {
    int off = 0;
    for (int q = cL3S[G]; q < pi; ++q) off += (2*cL1[cL3P[q]]+1)*(2*G+1);
    return off;
}
// max per-edge z total over groups: G3 = 196 -> 4*196 = 784 floats
// msg slice per group: 4*32*d3 <= 896 floats (G3). Union buffer = 896 floats/wave.

// R16 helpers: per-group slot -> path / z-offset / next-path (for A-prefetch chain)
constexpr int grpN (int G)        { return cL3S[G+1] - cL3S[G]; }
constexpr int pSlot(int G, int i) { return cL3P[cL3S[G] + i]; }
constexpr int zO   (int G, int i) { return zOff(G, cL3S[G] + i); }
constexpr int pNext(int G, int i) { return (i+1 < grpN(G)) ? cL3P[cL3S[G] + i + 1] : 0; }
constexpr bool pLast(int G, int i){ return i+1 == grpN(G); }

// ---- 8-point Gauss-Legendre nodes/weights (128-pt rule: exact for degree<=9 SH triple products) ----
__device__ const double GLX8[8] = {
    -0.96028985649753623168, -0.79666647741362673959, -0.52553240991632898582, -0.18343464249564980494,
     0.18343464249564980494,  0.52553240991632898582,  0.79666647741362673959,  0.96028985649753623168};
__device__ const double GLW8[8] = {
     0.10122853629037625915,  0.22238103445337447054,  0.31370664587788728734,  0.36268378337836198297,
     0.36268378337836198297,  0.31370664587788728734,  0.22238103445337447054,  0.10122853629037625915};
// cos/sin(k*pi/8), k=0..15 — exact literals
__device__ const double COSP16[16] = {
  1.0,                     0.92387953251128675613,  0.70710678118654752440,  0.38268343236508977173,
  0.0,                    -0.38268343236508977173, -0.70710678118654752440, -0.92387953251128675613,
 -1.0,                    -0.92387953251128675613, -0.70710678118654752440, -0.38268343236508977173,
  0.0,                     0.38268343236508977173,  0.70710678118654752440,  0.92387953251128675613};
__device__ const double SINP16[16] = {
  0.0,                     0.38268343236508977173,  0.70710678118654752440,  0.92387953251128675613,
  1.0,                     0.92387953251128675613,  0.70710678118654752440,  0.38268343236508977173,
  0.0,                    -0.38268343236508977173, -0.70710678118654752440, -0.92387953251128675613,
 -1.0,                    -0.92387953251128675613, -0.70710678118654752440, -0.38268343236508977173};

__device__ inline void sh_f64(double x, double y, double z, double* Y) {
    const double s3 = 1.7320508075688772935, s5 = 2.2360679774997896964,
                 s7 = 2.6457513110645905905, s15 = 3.8729833462074168852;
    const double c58 = 0.79056941504209483300, c38 = 0.61237243569579452455;
    Y[0] = 1.0;
    Y[1] = s3*x;  Y[2] = s3*y;  Y[3] = s3*z;
    Y[4] = s5*s3*x*z;  Y[5] = s5*s3*x*y;
    Y[6] = s5*(y*y - 0.5*(x*x + z*z));
    Y[7] = s5*s3*y*z;  Y[8] = s5*(s3/2.0)*(z*z - x*x);
    Y[9] = s7*c58*x*(3.0*z*z - x*x);
    Y[10]= s7*s15*x*y*z;
    Y[11]= s7*c38*x*(5.0*y*y - 1.0);
    Y[12]= s7*0.5*y*(5.0*y*y - 3.0);
    Y[13]= s7*c38*z*(5.0*y*y - 1.0);
    Y[14]= s7*(s15/2.0)*y*(z*z - x*x);
    Y[15]= s7*c58*z*(z*z - 3.0*x*x);
}

__device__ inline void sh_f32(float x, float y, float z, float* Y) {
    const float s3 = 1.73205080757f, s5 = 2.23606797750f, s7 = 2.64575131106f, s15 = 3.87298334621f;
    const float c58 = 0.79056941504f, c38 = 0.61237243570f;
    Y[0] = 1.0f;
    Y[1] = s3*x;  Y[2] = s3*y;  Y[3] = s3*z;
    Y[4] = s15*x*z;  Y[5] = s15*x*y;
    Y[6] = s5*(y*y - 0.5f*(x*x + z*z));
    Y[7] = s15*y*z;  Y[8] = s5*(s3*0.5f)*(z*z - x*x);
    Y[9] = s7*c58*x*(3.0f*z*z - x*x);
    Y[10]= s7*s15*x*y*z;
    Y[11]= s7*c38*x*(5.0f*y*y - 1.0f);
    Y[12]= s7*0.5f*y*(5.0f*y*y - 3.0f);
    Y[13]= s7*c38*z*(5.0f*y*y - 1.0f);
    Y[14]= s7*(s15*0.5f)*y*(z*z - x*x);
    Y[15]= s7*c58*z*(z*z - 3.0f*x*x);
}

__device__ inline unsigned short bf16rne(float x) {
    unsigned int u = __float_as_uint(x);
    unsigned int r = (u + 0x7FFFu + ((u >> 16) & 1u)) >> 16;
    return (unsigned short)r;
}
__device__ inline float bf16f(unsigned short h) {
    return __uint_as_float(((unsigned int)h) << 16);
}

// ---- setup: W3J tables (128-pt quadrature) + weight transpose + output zeroing ----
__global__ __launch_bounds__(512) void w3j_setup_kernel(
    const float* __restrict__ ww, const float* __restrict__ wb,
    float* __restrict__ g_w3j,
    unsigned short* __restrict__ Awhi, unsigned short* __restrict__ Awlo,
    unsigned short* __restrict__ Abhi, unsigned short* __restrict__ Ablo,
    float* __restrict__ out) {
    const int t = threadIdx.x;

    if (blockIdx.x >= N_PATHS) {   // zero-blocks
        const int b = blockIdx.x - N_PATHS;
        float4* o4 = (float4*)(out + (size_t)b * (N_NODES*FEAT/ZERO_BLOCKS));
#pragma unroll
        for (int r = 0; r < 4; ++r)
            o4[t + 512*r] = make_float4(0.f,0.f,0.f,0.f);
        return;
    }

    __shared__ float s_Yq[128][17];
    __shared__ float s_wq[128];
    __shared__ float s_part[256];
    __shared__ float red[256];
    __shared__ float s_scale;

    const int p = blockIdx.x;
    const int l1 = cL1[p], l2 = cL2[p];
    const int l3 = D_L3[p];
    const int d2 = 2*l2+1, d3 = 2*l3+1;
    const int csize = (2*l1+1)*d2*d3;
    const double step = 2.0*3.14159265358979323846/16.0;

    // weight transpose to A-layout [p][w][u], bf16 hi/lo split
#pragma unroll
    for (int r = 0; r < 2; ++r) {
        const int idx = t + 512*r;
        const int w = idx >> 5, u = idx & 31;
        const float vw = ww[p*1024 + u*32 + w];
        const float vb = wb[p*1024 + u*32 + w];
        const unsigned short hw = bf16rne(vw);
        const unsigned short hb = bf16rne(vb);
        const int o = p*1024 + w*32 + u;
        Awhi[o] = hw;  Awlo[o] = bf16rne(vw - bf16f(hw));
        Abhi[o] = hb;  Ablo[o] = bf16rne(vb - bf16f(hb));
    }

    // phase A: one quadrature point per thread (first 128 threads)
    if (t < 128) {
        const int iu = t >> 4, ip = t & 15;
        const double u = GLX8[iu];
        const double st = sqrt(fmax(1.0 - u*u, 0.0));
        double Y[16];
        sh_f64(st*COSP16[ip], st*SINP16[ip], u, Y);
#pragma unroll
        for (int i = 0; i < 16; ++i) s_Yq[t][i] = (float)Y[i];
        s_wq[t] = (float)(GLW8[iu] * step);
    }
    __syncthreads();

    // phase B: 4 threads/entry, 32 interleaved points each, shuffle-reduce
    const int entry0 = t >> 2, sub = t & 3;
#pragma unroll
    for (int pass = 0; pass < 2; ++pass) {
        const int entry = entry0 + pass*128;
        float acc = 0.f;
        if (entry < csize) {
            const int i = entry/(d2*d3); const int r = entry - i*(d2*d3);
            const int j = r/d3; const int k = r - j*d3;
            const int ai = l1*l1+i, bi = l2*l2+j, ci = l3*l3+k;
#pragma unroll 4
            for (int it = 0; it < 32; ++it) {
                const int q = it*4 + sub;
                acc = fmaf(s_wq[q] * s_Yq[q][ai] * s_Yq[q][bi], s_Yq[q][ci], acc);
            }
        }
        acc += __shfl_xor(acc, 1);
        acc += __shfl_xor(acc, 2);
        if (sub == 0 && entry < csize) s_part[entry] = acc;
    }
    __syncthreads();

    if (t < 256) { const float v = (t < csize) ? s_part[t] : 0.f; red[t] = v*v; }
    __syncthreads();
    for (int s = 128; s > 0; s >>= 1) {
        if (t < s) red[t] += red[t+s];
        __syncthreads();
    }
    if (t == 0) {
        const float pw = sqrtf((float)(2*l3+1) / ((float)CNT_L3[l3] * (float)HIDDEN));
        s_scale = pw / sqrtf(red[0]);
    }
    __syncthreads();
    if (t < csize) g_w3j[cCOFF[p] + t] = s_part[t] * s_scale;
}

// ---- batched z for one path (no sync): z[el][i][k] into group z buffer ----
template<int G, int P, int ZOFF>
__device__ __forceinline__ void do_zpath(
    int lane, const float* __restrict__ w3j, const float* sY, float* sz)
{
    constexpr int l1 = cL1[P], l2 = cL2[P];
    constexpr int d1 = 2*l1+1, d2 = 2*l2+1, d3 = 2*G+1;
    constexpr int zc = d1*d3;
#pragma unroll
    for (int base = 0; base < 4*zc; base += 64) {
        const int idx = base + lane;
        if (idx < 4*zc) {
            const int elz = idx / zc;          // const-div
            const int r = idx - elz*zc;
            const int i = r / d3, k = r - i*d3;
            const float* Cp = w3j + cCOFF[P] + i*(d2*d3) + k;
            const float* Yp = sY + elz*16 + l2*l2;
            float acc = 0.f;
#pragma unroll
            for (int j = 0; j < d2; ++j) acc = fmaf(Yp[j], Cp[j*d3], acc);
            sz[4*ZOFF + elz*zc + r] = acc;
        }
    }
}

// ---- A-operand register set (one path): 4 arrays x 2 K-chunks ----
struct AReg { bf16x8 wh[2], wl[2], bh[2], bl[2]; };

template<int P>
__device__ __forceinline__ AReg load_a(int avaddr,
    const unsigned short* __restrict__ Awhi, const unsigned short* __restrict__ Awlo,
    const unsigned short* __restrict__ Abhi, const unsigned short* __restrict__ Ablo)
{
    AReg a;
    const unsigned short* pwh = Awhi + P*1024;
    const unsigned short* pwl = Awlo + P*1024;
    const unsigned short* pbh = Abhi + P*1024;
    const unsigned short* pbl = Ablo + P*1024;
#pragma unroll
    for (int kc = 0; kc < 2; ++kc) {
        a.wh[kc] = *(const bf16x8*)(pwh + avaddr + kc*16);
        a.wl[kc] = *(const bf16x8*)(pwl + avaddr + kc*16);
        a.bh[kc] = *(const bf16x8*)(pbh + avaddr + kc*16);
        a.bl[kc] = *(const bf16x8*)(pbl + avaddr + kc*16);
    }
    return a;
}

// ---- one path: NEXT-A prefetch -> tmp/stage -> 32x32 MFMA with current A ----
// Fence discipline identical to R11; A-chain/setprio from R16.
template<int G, int P, int ZOFF, int PNEXT, bool LAST>
__device__ __forceinline__ void do_path(
    int lane, int el4, int u0, int bvaddr, int avaddr,
    const float (&xr0)[16], const float (&xr1)[16],
    const unsigned short* __restrict__ Awhi, const unsigned short* __restrict__ Awlo,
    const unsigned short* __restrict__ Abhi, const unsigned short* __restrict__ Ablo,
    const float* sz,
    unsigned short* sbh, unsigned short* sbl,
    f32x16 &Cw, f32x16 &Cb, AReg &a)
{
    constexpr int l1 = cL1[P];
    constexpr int d1 = 2*l1+1, d3 = 2*G+1;
    constexpr int zc = d1*d3;
    constexpr int xo = l1*l1;

    // issue NEXT path's A-loads now (global/L2) — deep prefetch
    AReg an;
    if constexpr (!LAST)
        an = load_a<PNEXT>(avaddr, Awhi, Awlo, Abhi, Ablo);

    // tmp[u][k] = sum_i x[u,i]*z[i,k] for u=2u0,2u0+1; chop-split bf16; packed u32 stores
    {
        const float* zr = sz + 4*ZOFF + el4*zc;
        unsigned short* bh = sbh + (el4*d3)*40 + 2*u0;
        unsigned short* bl = sbl + (el4*d3)*40 + 2*u0;
#pragma unroll
        for (int k = 0; k < d3; ++k) {
            float t0 = 0.f, t1 = 0.f;
#pragma unroll
            for (int i = 0; i < d1; ++i) {
                const float zz = zr[i*d3 + k];
                t0 = fmaf(xr0[xo+i], zz, t0);
                t1 = fmaf(xr1[xo+i], zz, t1);
            }
            const unsigned int b0 = __float_as_uint(t0);
            const unsigned int b1 = __float_as_uint(t1);
            const float l0 = t0 - __uint_as_float(b0 & 0xFFFF0000u);
            const float l1f = t1 - __uint_as_float(b1 & 0xFFFF0000u);
            *(unsigned int*)(bh + k*40) = (b0 >> 16) | (b1 & 0xFFFF0000u);
            *(unsigned int*)(bl + k*40) = (__float_as_uint(l0) >> 16) | (__float_as_uint(l1f) & 0xFFFF0000u);
        }
    }
    WAVE_SYNC();

    // B loads + 12 MFMA (2 K-chunks x 3-pass hi/lo x {w,b}), interleaved dual chains
    __builtin_amdgcn_s_setprio(1);
#pragma unroll
    for (int kc = 0; kc < 2; ++kc) {
        const bf16x8 bh = *(const bf16x8*)(sbh + bvaddr + kc*16);
        const bf16x8 bl = *(const bf16x8*)(sbl + bvaddr + kc*16);
        Cw = __builtin_amdgcn_mfma_f32_32x32x16_bf16(a.wh[kc], bh, Cw, 0, 0, 0);
        Cb = __builtin_amdgcn_mfma_f32_32x32x16_bf16(a.bh[kc], bh, Cb, 0, 0, 0);
        Cw = __builtin_amdgcn_mfma_f32_32x32x16_bf16(a.wh[kc], bl, Cw, 0, 0, 0);
        Cb = __builtin_amdgcn_mfma_f32_32x32x16_bf16(a.bh[kc], bl, Cb, 0, 0, 0);
        Cw = __builtin_amdgcn_mfma_f32_32x32x16_bf16(a.wl[kc], bh, Cw, 0, 0, 0);
        Cb = __builtin_amdgcn_mfma_f32_32x32x16_bf16(a.bl[kc], bh, Cb, 0, 0, 0);
    }
    __builtin_amdgcn_s_setprio(0);
    WAVE_SYNC();  // B reads done before next path's stage overwrites

    if constexpr (!LAST) a = an;   // advance the A-chain
}

// ---- one l3 group: A[0] preload -> batched z (1 sync) -> chained per-path tmp+MFMA.
// R18: epilogue writes into the z buffer (dead after last tmp) and flushes the
// group's slice to global with coalesced atomics — s_msg eliminated (LDS diet).
template<int G>
__device__ __forceinline__ void do_group(
    int lane, int el4, int u0, int bvaddr, int avaddr,
    const float (&xr0)[16], const float (&xr1)[16],
    const float* __restrict__ w3j,
    const unsigned short* __restrict__ Awhi, const unsigned short* __restrict__ Awlo,
    const unsigned short* __restrict__ Abhi, const unsigned short* __restrict__ Ablo,
    const float* sY, float* sz,
    unsigned short* sbh, unsigned short* sbl,
    const float* slen, const int* sdst, float* __restrict__ out)
{
    constexpr int d3 = 2*G+1;
    constexpr int n = grpN(G);
    f32x16 Cw = (f32x16)(0.f), Cb = (f32x16)(0.f);

    // first path's A issued BEFORE the z phase: the whole z VALU block hides L2 latency
    AReg a = load_a<pSlot(G,0)>(avaddr, Awhi, Awlo, Abhi, Ablo);

    // batched z: all paths of the group, single sync
    do_zpath<G, pSlot(G,0), zO(G,0)>(lane, w3j, sY, sz);
    do_zpath<G, pSlot(G,1), zO(G,1)>(lane, w3j, sY, sz);
    do_zpath<G, pSlot(G,2), zO(G,2)>(lane, w3j, sY, sz);
    do_zpath<G, pSlot(G,3), zO(G,3)>(lane, w3j, sY, sz);
    if constexpr (n > 4) do_zpath<G, pSlot(G,4), zO(G,4)>(lane, w3j, sY, sz);
    if constexpr (n > 5) do_zpath<G, pSlot(G,5), zO(G,5)>(lane, w3j, sY, sz);
    if constexpr (n > 6) do_zpath<G, pSlot(G,6), zO(G,6)>(lane, w3j, sY, sz);
    WAVE_SYNC();

    do_path<G, pSlot(G,0), zO(G,0), pNext(G,0), pLast(G,0)>(lane,el4,u0,bvaddr,avaddr,xr0,xr1,Awhi,Awlo,Abhi,Ablo,sz,sbh,sbl,Cw,Cb,a);
    do_path<G, pSlot(G,1), zO(G,1), pNext(G,1), pLast(G,1)>(lane,el4,u0,bvaddr,avaddr,xr0,xr1,Awhi,Awlo,Abhi,Ablo,sz,sbh,sbl,Cw,Cb,a);
    do_path<G, pSlot(G,2), zO(G,2), pNext(G,2), pLast(G,2)>(lane,el4,u0,bvaddr,avaddr,xr0,xr1,Awhi,Awlo,Abhi,Ablo,sz,sbh,sbl,Cw,Cb,a);
    do_path<G, pSlot(G,3), zO(G,3), pNext(G,3), pLast(G,3)>(lane,el4,u0,bvaddr,avaddr,xr0,xr1,Awhi,Awlo,Abhi,Ablo,sz,sbh,sbl,Cw,Cb,a);
    if constexpr (n > 4)
        do_path<G, pSlot(G,4), zO(G,4), pNext(G,4), pLast(G,4)>(lane,el4,u0,bvaddr,avaddr,xr0,xr1,Awhi,Awlo,Abhi,Ablo,sz,sbh,sbl,Cw,Cb,a);
    if constexpr (n > 5)
        do_path<G, pSlot(G,5), zO(G,5), pNext(G,5), pLast(G,5)>(lane,el4,u0,bvaddr,avaddr,xr0,xr1,Awhi,Awlo,Abhi,Ablo,sz,sbh,sbl,Cw,Cb,a);
    if constexpr (n > 6)
        do_path<G, pSlot(G,6), zO(G,6), pNext(G,6), pLast(G,6)>(lane,el4,u0,bvaddr,avaddr,xr0,xr1,Awhi,Awlo,Abhi,Ablo,sz,sbh,sbl,Cw,Cb,a);

    // epilogue: msg = len*Cw + Cb into the z-aliased slice [el][w][k]
    // (z region is quiescent: the last do_path's trailing WAVE_SYNC drained all z reads)
    // C/D layout (verified m74/m101): col=lane&31, row=(reg&3)+8*(reg>>2)+4*(lane>>5)
    constexpr int gsz = 32*d3;
    const int col = lane & 31;
    if (col < 4*d3) {
        const int elc = col / d3, k = col - elc*d3;   // const-div
        const float len = slen[elc];
        float* mp = sz + elc*gsz + k;
#pragma unroll
        for (int reg = 0; reg < 16; ++reg) {
            const int w = (reg & 3) + 8*(reg >> 2) + 4*(lane >> 5);
            mp[w*d3] = fmaf(len, Cw[reg], Cb[reg]);
        }
    }
    WAVE_SYNC();   // slice writes complete before flush reads

    // per-group coalesced atomic flush (same total atomics as R11's tail scatter)
    for (int i2 = lane; i2 < 4*gsz; i2 += 64) {
        const int el = i2 / gsz;                      // const-div
        const int m  = i2 - el*gsz;
        atomicAdd(&out[(size_t)sdst[el]*FEAT + cOFF3[G] + m], sz[i2]);
    }
    WAVE_SYNC();   // flush reads done before next group's z overwrites
}

// ---- main: 2 waves/block, 4 edges/wave (R11 + R16 A-chain/setprio + R18 LDS diet) ----
__global__ __launch_bounds__(BLK, 4) void edge_kernel(
    const float* __restrict__ nf,
    const int*   __restrict__ eidx,
    const float* __restrict__ ev,
    const float* __restrict__ w3j,
    const unsigned short* __restrict__ Awhi,
    const unsigned short* __restrict__ Awlo,
    const unsigned short* __restrict__ Abhi,
    const unsigned short* __restrict__ Ablo,
    float*       __restrict__ out)
{
    __shared__ float s_zp[2][896];       // union: per-group z (<=784) / msg slice (<=896)
    __shared__ float s_Y[2][64];
    __shared__ float s_len[2][4];
    __shared__ int   s_src[2][4];
    __shared__ int   s_dst[2][4];
    __shared__ __align__(16) unsigned short s_Bhi[2][1280];  // [col(32)][u(32)+pad8]
    __shared__ __align__(16) unsigned short s_Blo[2][1280];

    const int t    = threadIdx.x;
    const int wave = t >> 6;
    const int lane = t & 63;
    const int el4  = lane >> 4;      // tmp-phase edge (4 per wave)
    const int u0   = lane & 15;      // tmp-phase u-pair index
    const int e0   = blockIdx.x * 8 + wave*4;
    const int bvaddr = (lane & 31)*40 + (lane >> 5)*8;   // B: n=lane&31, k0=(lane>>5)*8
    const int avaddr = (lane & 31)*32 + (lane >> 5)*8;   // A: m=lane&31, k0=(lane>>5)*8

    if (lane < 4) {
        const int e = e0 + lane;
        s_src[wave][lane] = eidx[e];
        s_dst[wave][lane] = eidx[N_EDGES + e];
        const float x = ev[e*3+0], y = ev[e*3+1], z = ev[e*3+2];
        const float len = sqrtf(x*x + y*y + z*z);
        const float lc = fmaxf(len, 1e-8f);
        s_len[wave][lane] = lc;
        float Yl[16];
        sh_f32(x/lc, y/lc, z/lc, Yl);
#pragma unroll
        for (int i = 0; i < 16; ++i) s_Y[wave][lane*16+i] = Yl[i];
    }
    WAVE_SYNC();

    // preload this lane's 2 u-rows of x (u = 2u0, 2u0+1) into registers
    float xr0[16], xr1[16];
    {
        const float* xrow = nf + (size_t)s_src[wave][el4]*FEAT;
        const int ua = 2*u0, ub = 2*u0 + 1;
        xr0[0] = xrow[ua];                 xr1[0] = xrow[ub];
#pragma unroll
        for (int i = 0; i < 3; ++i) { xr0[1+i] = xrow[32 + ua*3 + i];  xr1[1+i] = xrow[32 + ub*3 + i]; }
#pragma unroll
        for (int i = 0; i < 5; ++i) { xr0[4+i] = xrow[128 + ua*5 + i]; xr1[4+i] = xrow[128 + ub*5 + i]; }
#pragma unroll
        for (int i = 0; i < 7; ++i) { xr0[9+i] = xrow[288 + ua*7 + i]; xr1[9+i] = xrow[288 + ub*7 + i]; }
    }

    do_group<0>(lane,el4,u0,bvaddr,avaddr,xr0,xr1,w3j,Awhi,Awlo,Abhi,Ablo,
                s_Y[wave], s_zp[wave], s_Bhi[wave], s_Blo[wave], s_len[wave], s_dst[wave], out);
    do_group<1>(lane,el4,u0,bvaddr,avaddr,xr0,xr1,w3j,Awhi,Awlo,Abhi,Ablo,
                s_Y[wave], s_zp[wave], s_Bhi[wave], s_Blo[wave], s_len[wave], s_dst[wave], out);
    do_group<2>(lane,el4,u0,bvaddr,avaddr,xr0,xr1,w3j,Awhi,Awlo,Abhi,Ablo,
                s_Y[wave], s_zp[wave], s_Bhi[wave], s_Blo[wave], s_len[wave], s_dst[wave], out);
    do_group<3>(lane,el4,u0,bvaddr,avaddr,xr0,xr1,w3j,Awhi,Awlo,Abhi,Ablo,
                s_Y[wave], s_zp[wave], s_Bhi[wave], s_Blo[wave], s_len[wave], s_dst[wave], out);
}

extern "C" void kernel_launch(void* const* d_in, const int* in_sizes, int n_in,
                              void* d_out, int out_size, void* d_ws, size_t ws_size,
                              hipStream_t stream) {
    const float* nf   = (const float*)d_in[0];
    const int*   eidx = (const int*)  d_in[1];
    const float* ev   = (const float*)d_in[2];
    const float* ww   = (const float*)d_in[3];
    const float* wb   = (const float*)d_in[4];
    float* out = (float*)d_out;

    float* w3j = (float*)d_ws;                                   // 7500 B
    unsigned short* Awhi = (unsigned short*)((char*)d_ws + 16384);
    unsigned short* Awlo = Awhi + N_PATHS*1024;
    unsigned short* Abhi = Awlo + N_PATHS*1024;
    unsigned short* Ablo = Abhi + N_PATHS*1024;                  // ends at 204800 B

    w3j_setup_kernel<<<N_PATHS + ZERO_BLOCKS, 512, 0, stream>>>(
        ww, wb, w3j, Awhi, Awlo, Abhi, Ablo, out);
    edge_kernel<<<N_EDGES/8, BLK, 0, stream>>>(nf, eidx, ev, w3j, Awhi, Awlo, Abhi, Ablo, out);
}

// Round 8
// 145.663 us; speedup vs baseline: 1.1916x; 1.1916x over previous
//
#include <hip/hip_runtime.h>
#include <math.h>

#define N_PATHS 23
#define HIDDEN  32
#define N_NODES 4096
#define N_EDGES 8192
#define FEAT    512
#define BLK     128   // 2 waves share 4 edges; waves split u(K)-dim (R19); grid 2048 -> 8 blk/CU
#define ZERO_BLOCKS 256

// wave-local LDS phase separator (all prior DS ops complete)
#define WAVE_SYNC() asm volatile("s_waitcnt lgkmcnt(0)" ::: "memory")

typedef __attribute__((ext_vector_type(8)))  short bf16x8;
typedef __attribute__((ext_vector_type(16))) float f32x16;

// ---- compile-time path metadata (PATHS enumeration: l1 outer, l2, l3) ----
constexpr int cL1[N_PATHS] = {0,0,0,0, 1,1,1,1,1,1, 2,2,2,2,2,2,2, 3,3,3,3,3,3};
constexpr int cL2[N_PATHS] = {0,1,2,3, 0,1,1,2,2,3, 0,1,1,2,2,3,3, 0,1,2,2,3,3};
constexpr int cCOFF[N_PATHS]= {0,1,10,35,84,93,102,147,192,297,402,427,472,577,602,727,832,1077,1126,1231,1336,1581,1630};
constexpr int cL3P[N_PATHS] = {0,5,13,21, 1,4,7,11,15,19, 2,6,9,10,14,18,22, 3,8,12,16,17,20};
constexpr int cL3S[5] = {0,4,10,17,23};
constexpr int cOFF3[4] = {0,32,128,288};
__device__ const int CNT_L3[4] = {4,6,7,6};
__device__ const int D_L3[N_PATHS] = {0,1,2,3, 1,0,2,1,3,2, 2,1,3,0,2,1,3, 3,2,1,3,0,2};

// per-edge z offset of path slot pi within its group's batched z buffer
constexpr int zOff(int G, int pi) {
    int off = 0;
    for (int q = cL3S[G]; q < pi; ++q) off += (2*cL1[cL3P[q]]+1)*(2*G+1);
    return off;
}
// max per-edge z total over groups: G3 = 196 -> 4*196 = 784 floats (shared, block-coop)

constexpr int grpN (int G)        { return cL3S[G+1] - cL3S[G]; }
constexpr int pSlot(int G, int i) { return cL3P[cL3S[G] + i]; }
constexpr int zO   (int G, int i) { return zOff(G, cL3S[G] + i); }

// B-buffer stride: 16 u's + pad -> 24 shorts (48 B, 16B-aligned for ds_read_b128)
#define BSTR 24

// ---- 8-point Gauss-Legendre nodes/weights (128-pt rule: exact for degree<=9 SH triple products) ----
__device__ const double GLX8[8] = {
    -0.96028985649753623168, -0.79666647741362673959, -0.52553240991632898582, -0.18343464249564980494,
     0.18343464249564980494,  0.52553240991632898582,  0.79666647741362673959,  0.96028985649753623168};
__device__ const double GLW8[8] = {
     0.10122853629037625915,  0.22238103445337447054,  0.31370664587788728734,  0.36268378337836198297,
     0.36268378337836198297,  0.31370664587788728734,  0.22238103445337447054,  0.10122853629037625915};
// cos/sin(k*pi/8), k=0..15 — exact literals
__device__ const double COSP16[16] = {
  1.0,                     0.92387953251128675613,  0.70710678118654752440,  0.38268343236508977173,
  0.0,                    -0.38268343236508977173, -0.70710678118654752440, -0.92387953251128675613,
 -1.0,                    -0.92387953251128675613, -0.70710678118654752440, -0.38268343236508977173,
  0.0,                     0.38268343236508977173,  0.70710678118654752440,  0.92387953251128675613};
__device__ const double SINP16[16] = {
  0.0,                     0.38268343236508977173,  0.70710678118654752440,  0.92387953251128675613,
  1.0,                     0.92387953251128675613,  0.70710678118654752440,  0.38268343236508977173,
  0.0,                    -0.38268343236508977173, -0.70710678118654752440, -0.92387953251128675613,
 -1.0,                    -0.92387953251128675613, -0.70710678118654752440, -0.38268343236508977173};

__device__ inline void sh_f64(double x, double y, double z, double* Y) {
    const double s3 = 1.7320508075688772935, s5 = 2.2360679774997896964,
                 s7 = 2.6457513110645905905, s15 = 3.8729833462074168852;
    const double c58 = 0.79056941504209483300, c38 = 0.61237243569579452455;
    Y[0] = 1.0;
    Y[1] = s3*x;  Y[2] = s3*y;  Y[3] = s3*z;
    Y[4] = s5*s3*x*z;  Y[5] = s5*s3*x*y;
    Y[6] = s5*(y*y - 0.5*(x*x + z*z));
    Y[7] = s5*s3*y*z;  Y[8] = s5*(s3/2.0)*(z*z - x*x);
    Y[9] = s7*c58*x*(3.0*z*z - x*x);
    Y[10]= s7*s15*x*y*z;
    Y[11]= s7*c38*x*(5.0*y*y - 1.0);
    Y[12]= s7*0.5*y*(5.0*y*y - 3.0);
    Y[13]= s7*c38*z*(5.0*y*y - 1.0);
    Y[14]= s7*(s15/2.0)*y*(z*z - x*x);
    Y[15]= s7*c58*z*(z*z - 3.0*x*x);
}

__device__ inline void sh_f32(float x, float y, float z, float* Y) {
    const float s3 = 1.73205080757f, s5 = 2.23606797750f, s7 = 2.64575131106f, s15 = 3.87298334621f;
    const float c58 = 0.79056941504f, c38 = 0.61237243570f;
    Y[0] = 1.0f;
    Y[1] = s3*x;  Y[2] = s3*y;  Y[3] = s3*z;
    Y[4] = s15*x*z;  Y[5] = s15*x*y;
    Y[6] = s5*(y*y - 0.5f*(x*x + z*z));
    Y[7] = s15*y*z;  Y[8] = s5*(s3*0.5f)*(z*z - x*x);
    Y[9] = s7*c58*x*(3.0f*z*z - x*x);
    Y[10]= s7*s15*x*y*z;
    Y[11]= s7*c38*x*(5.0f*y*y - 1.0f);
    Y[12]= s7*0.5f*y*(5.0f*y*y - 3.0f);
    Y[13]= s7*c38*z*(5.0f*y*y - 1.0f);
    Y[14]= s7*(s15*0.5f)*y*(z*z - x*x);
    Y[15]= s7*c58*z*(z*z - 3.0f*x*x);
}

__device__ inline unsigned short bf16rne(float x) {
    unsigned int u = __float_as_uint(x);
    unsigned int r = (u + 0x7FFFu + ((u >> 16) & 1u)) >> 16;
    return (unsigned short)r;
}
__device__ inline float bf16f(unsigned short h) {
    return __uint_as_float(((unsigned int)h) << 16);
}

// ---- setup: W3J tables (128-pt quadrature) + weight transpose + output zeroing ----
__global__ __launch_bounds__(512) void w3j_setup_kernel(
    const float* __restrict__ ww, const float* __restrict__ wb,
    float* __restrict__ g_w3j,
    unsigned short* __restrict__ Awhi, unsigned short* __restrict__ Awlo,
    unsigned short* __restrict__ Abhi, unsigned short* __restrict__ Ablo,
    float* __restrict__ out) {
    const int t = threadIdx.x;

    if (blockIdx.x >= N_PATHS) {   // zero-blocks
        const int b = blockIdx.x - N_PATHS;
        float4* o4 = (float4*)(out + (size_t)b * (N_NODES*FEAT/ZERO_BLOCKS));
#pragma unroll
        for (int r = 0; r < 4; ++r)
            o4[t + 512*r] = make_float4(0.f,0.f,0.f,0.f);
        return;
    }

    __shared__ float s_Yq[128][17];
    __shared__ float s_wq[128];
    __shared__ float s_part[256];
    __shared__ float red[256];
    __shared__ float s_scale;

    const int p = blockIdx.x;
    const int l1 = cL1[p], l2 = cL2[p];
    const int l3 = D_L3[p];
    const int d2 = 2*l2+1, d3 = 2*l3+1;
    const int csize = (2*l1+1)*d2*d3;
    const double step = 2.0*3.14159265358979323846/16.0;

    // weight transpose to A-layout [p][w][u], bf16 hi/lo split
#pragma unroll
    for (int r = 0; r < 2; ++r) {
        const int idx = t + 512*r;
        const int w = idx >> 5, u = idx & 31;
        const float vw = ww[p*1024 + u*32 + w];
        const float vb = wb[p*1024 + u*32 + w];
        const unsigned short hw = bf16rne(vw);
        const unsigned short hb = bf16rne(vb);
        const int o = p*1024 + w*32 + u;
        Awhi[o] = hw;  Awlo[o] = bf16rne(vw - bf16f(hw));
        Abhi[o] = hb;  Ablo[o] = bf16rne(vb - bf16f(hb));
    }

    // phase A: one quadrature point per thread (first 128 threads)
    if (t < 128) {
        const int iu = t >> 4, ip = t & 15;
        const double u = GLX8[iu];
        const double st = sqrt(fmax(1.0 - u*u, 0.0));
        double Y[16];
        sh_f64(st*COSP16[ip], st*SINP16[ip], u, Y);
#pragma unroll
        for (int i = 0; i < 16; ++i) s_Yq[t][i] = (float)Y[i];
        s_wq[t] = (float)(GLW8[iu] * step);
    }
    __syncthreads();

    // phase B: 4 threads/entry, 32 interleaved points each, shuffle-reduce
    const int entry0 = t >> 2, sub = t & 3;
#pragma unroll
    for (int pass = 0; pass < 2; ++pass) {
        const int entry = entry0 + pass*128;
        float acc = 0.f;
        if (entry < csize) {
            const int i = entry/(d2*d3); const int r = entry - i*(d2*d3);
            const int j = r/d3; const int k = r - j*d3;
            const int ai = l1*l1+i, bi = l2*l2+j, ci = l3*l3+k;
#pragma unroll 4
            for (int it = 0; it < 32; ++it) {
                const int q = it*4 + sub;
                acc = fmaf(s_wq[q] * s_Yq[q][ai] * s_Yq[q][bi], s_Yq[q][ci], acc);
            }
        }
        acc += __shfl_xor(acc, 1);
        acc += __shfl_xor(acc, 2);
        if (sub == 0 && entry < csize) s_part[entry] = acc;
    }
    __syncthreads();

    if (t < 256) { const float v = (t < csize) ? s_part[t] : 0.f; red[t] = v*v; }
    __syncthreads();
    for (int s = 128; s > 0; s >>= 1) {
        if (t < s) red[t] += red[t+s];
        __syncthreads();
    }
    if (t == 0) {
        const float pw = sqrtf((float)(2*l3+1) / ((float)CNT_L3[l3] * (float)HIDDEN));
        s_scale = pw / sqrtf(red[0]);
    }
    __syncthreads();
    if (t < csize) g_w3j[cCOFF[p] + t] = s_part[t] * s_scale;
}

// ---- batched z for one path: block-cooperative (128 threads), no sync inside ----
template<int G, int P, int ZOFF>
__device__ __forceinline__ void do_zpath(
    int t, const float* __restrict__ w3j, const float* sY, float* sz)
{
    constexpr int l1 = cL1[P], l2 = cL2[P];
    constexpr int d1 = 2*l1+1, d2 = 2*l2+1, d3 = 2*G+1;
    constexpr int zc = d1*d3;
#pragma unroll
    for (int base = 0; base < 4*zc; base += 128) {
        const int idx = base + t;
        if (idx < 4*zc) {
            const int elz = idx / zc;          // const-div
            const int r = idx - elz*zc;
            const int i = r / d3, k = r - i*d3;
            const float* Cp = w3j + cCOFF[P] + i*(d2*d3) + k;
            const float* Yp = sY + elz*16 + l2*l2;
            float acc = 0.f;
#pragma unroll
            for (int j = 0; j < d2; ++j) acc = fmaf(Yp[j], Cp[j*d3], acc);
            sz[4*ZOFF + elz*zc + r] = acc;
        }
    }
}

// ---- one path, ONE u-half (16 u's, K=16): A loads -> tmp/stage -> 6 MFMA ----
// Fence discipline = R11 (per-wave, wave-local buffers).
template<int G, int P, int ZOFF>
__device__ __forceinline__ void do_path(
    int lane, int el4, int ul, int bvaddr, int avaddr,
    const float (&xr)[16],
    const unsigned short* __restrict__ Awhi, const unsigned short* __restrict__ Awlo,
    const unsigned short* __restrict__ Abhi, const unsigned short* __restrict__ Ablo,
    const float* sz,
    unsigned short* sbh, unsigned short* sbl,
    f32x16 &Cw, f32x16 &Cb)
{
    constexpr int l1 = cL1[P];
    constexpr int d1 = 2*l1+1, d3 = 2*G+1;
    constexpr int zc = d1*d3;
    constexpr int xo = l1*l1;

    // A-operand loads (global/L2) BEFORE the tmp VALU block hides their latency
    const bf16x8 awh = *(const bf16x8*)(Awhi + P*1024 + avaddr);
    const bf16x8 awl = *(const bf16x8*)(Awlo + P*1024 + avaddr);
    const bf16x8 abh = *(const bf16x8*)(Abhi + P*1024 + avaddr);
    const bf16x8 abl = *(const bf16x8*)(Ablo + P*1024 + avaddr);

    // tmp[u][k] = sum_i x[u,i]*z[i,k] for this lane's single u; chop-split bf16
    {
        const float* zr = sz + 4*ZOFF + el4*zc;
        unsigned short* bh = sbh + (el4*d3)*BSTR + ul;
        unsigned short* bl = sbl + (el4*d3)*BSTR + ul;
#pragma unroll
        for (int k = 0; k < d3; ++k) {
            float t0 = 0.f;
#pragma unroll
            for (int i = 0; i < d1; ++i)
                t0 = fmaf(xr[xo+i], zr[i*d3 + k], t0);
            const unsigned int b0 = __float_as_uint(t0);
            const float l0 = t0 - __uint_as_float(b0 & 0xFFFF0000u);
            bh[k*BSTR] = (unsigned short)(b0 >> 16);
            bl[k*BSTR] = (unsigned short)(__float_as_uint(l0) >> 16);
        }
    }
    WAVE_SYNC();

    // B loads + 6 MFMA (3-pass hi/lo x {w,b}), interleaved dual chains
    __builtin_amdgcn_s_setprio(1);
    const bf16x8 bhv = *(const bf16x8*)(sbh + bvaddr);
    const bf16x8 blv = *(const bf16x8*)(sbl + bvaddr);
    Cw = __builtin_amdgcn_mfma_f32_32x32x16_bf16(awh, bhv, Cw, 0, 0, 0);
    Cb = __builtin_amdgcn_mfma_f32_32x32x16_bf16(abh, bhv, Cb, 0, 0, 0);
    Cw = __builtin_amdgcn_mfma_f32_32x32x16_bf16(awh, blv, Cw, 0, 0, 0);
    Cb = __builtin_amdgcn_mfma_f32_32x32x16_bf16(abh, blv, Cb, 0, 0, 0);
    Cw = __builtin_amdgcn_mfma_f32_32x32x16_bf16(awl, bhv, Cw, 0, 0, 0);
    Cb = __builtin_amdgcn_mfma_f32_32x32x16_bf16(abl, bhv, Cb, 0, 0, 0);
    __builtin_amdgcn_s_setprio(0);
    WAVE_SYNC();  // B reads done before next path's stage overwrites
}

// ---- one l3 group: block-coop z (1 barrier), per-path tmp+MFMA (wave-local),
// epilogue: u-half partials combined in shared s_msg via LDS atomics (R19) ----
template<int G>
__device__ __forceinline__ void do_group(
    int t, int lane, int el4, int ul, int bvaddr, int avaddr,
    const float (&xr)[16],
    const float* __restrict__ w3j,
    const unsigned short* __restrict__ Awhi, const unsigned short* __restrict__ Awlo,
    const unsigned short* __restrict__ Abhi, const unsigned short* __restrict__ Ablo,
    const float* sY, float* sz,
    unsigned short* sbh, unsigned short* sbl,
    const float* slen, float* smsg)
{
    constexpr int d3 = 2*G+1;
    constexpr int n = grpN(G);
    f32x16 Cw = (f32x16)(0.f), Cb = (f32x16)(0.f);

    // batched z: all paths of the group, block-cooperative, single barrier
    do_zpath<G, pSlot(G,0), zO(G,0)>(t, w3j, sY, sz);
    do_zpath<G, pSlot(G,1), zO(G,1)>(t, w3j, sY, sz);
    do_zpath<G, pSlot(G,2), zO(G,2)>(t, w3j, sY, sz);
    do_zpath<G, pSlot(G,3), zO(G,3)>(t, w3j, sY, sz);
    if constexpr (n > 4) do_zpath<G, pSlot(G,4), zO(G,4)>(t, w3j, sY, sz);
    if constexpr (n > 5) do_zpath<G, pSlot(G,5), zO(G,5)>(t, w3j, sY, sz);
    if constexpr (n > 6) do_zpath<G, pSlot(G,6), zO(G,6)>(t, w3j, sY, sz);
    __syncthreads();

    do_path<G, pSlot(G,0), zO(G,0)>(lane,el4,ul,bvaddr,avaddr,xr,Awhi,Awlo,Abhi,Ablo,sz,sbh,sbl,Cw,Cb);
    do_path<G, pSlot(G,1), zO(G,1)>(lane,el4,ul,bvaddr,avaddr,xr,Awhi,Awlo,Abhi,Ablo,sz,sbh,sbl,Cw,Cb);
    do_path<G, pSlot(G,2), zO(G,2)>(lane,el4,ul,bvaddr,avaddr,xr,Awhi,Awlo,Abhi,Ablo,sz,sbh,sbl,Cw,Cb);
    do_path<G, pSlot(G,3), zO(G,3)>(lane,el4,ul,bvaddr,avaddr,xr,Awhi,Awlo,Abhi,Ablo,sz,sbh,sbl,Cw,Cb);
    if constexpr (n > 4)
        do_path<G, pSlot(G,4), zO(G,4)>(lane,el4,ul,bvaddr,avaddr,xr,Awhi,Awlo,Abhi,Ablo,sz,sbh,sbl,Cw,Cb);
    if constexpr (n > 5)
        do_path<G, pSlot(G,5), zO(G,5)>(lane,el4,ul,bvaddr,avaddr,xr,Awhi,Awlo,Abhi,Ablo,sz,sbh,sbl,Cw,Cb);
    if constexpr (n > 6)
        do_path<G, pSlot(G,6), zO(G,6)>(lane,el4,ul,bvaddr,avaddr,xr,Awhi,Awlo,Abhi,Ablo,sz,sbh,sbl,Cw,Cb);

    // epilogue: smsg += len*Cw + Cb (this wave's u-half partial; ds_add combines)
    // C/D layout (verified m74/m101): col=lane&31, row=(reg&3)+8*(reg>>2)+4*(lane>>5)
    const int col = lane & 31;
    if (col < 4*d3) {
        const int elc = col / d3, k = col - elc*d3;   // const-div
        const float len = slen[elc];
        float* mp = smsg + elc*FEAT + cOFF3[G] + k;
#pragma unroll
        for (int reg = 0; reg < 16; ++reg) {
            const int w = (reg & 3) + 8*(reg >> 2) + 4*(lane >> 5);
            atomicAdd(&mp[w*d3], fmaf(len, Cw[reg], Cb[reg]));
        }
    }
    __syncthreads();   // all s_zp reads done before next group's z overwrites
}

// ---- main: 2 waves/block, 4 edges/BLOCK, waves split u(K) (R19) ----
__global__ __launch_bounds__(BLK, 4) void edge_kernel(
    const float* __restrict__ nf,
    const int*   __restrict__ eidx,
    const float* __restrict__ ev,
    const float* __restrict__ w3j,
    const unsigned short* __restrict__ Awhi,
    const unsigned short* __restrict__ Awlo,
    const unsigned short* __restrict__ Abhi,
    const unsigned short* __restrict__ Ablo,
    float*       __restrict__ out)
{
    __shared__ float s_zp[784];          // shared batched per-group z (block-coop)
    __shared__ float s_Y[64];
    __shared__ float s_len[4];
    __shared__ int   s_src[4];
    __shared__ int   s_dst[4];
    __shared__ __align__(16) unsigned short s_Bhi[2][32*BSTR];  // per-wave [col(32)][u16+pad8]
    __shared__ __align__(16) unsigned short s_Blo[2][32*BSTR];
    __shared__ float s_msg[4*FEAT];      // shared partial-sum buffer (ds_add_f32)

    const int t    = threadIdx.x;
    const int wave = t >> 6;
    const int lane = t & 63;
    const int el4  = lane >> 4;      // tmp-phase edge (4 per block)
    const int ul   = lane & 15;      // tmp-phase local u; global u = 16*wave + ul
    const int e0   = blockIdx.x * 4;
    const int bvaddr = (lane & 31)*BSTR + (lane >> 5)*8;           // B: n=lane&31, k0=(lane>>5)*8
    const int avaddr = (lane & 31)*32 + 16*wave + (lane >> 5)*8;   // A: m=lane&31, u=16w+k0

    if (t < 4) {
        const int e = e0 + t;
        s_src[t] = eidx[e];
        s_dst[t] = eidx[N_EDGES + e];
        const float x = ev[e*3+0], y = ev[e*3+1], z = ev[e*3+2];
        const float len = sqrtf(x*x + y*y + z*z);
        const float lc = fmaxf(len, 1e-8f);
        s_len[t] = lc;
        float Yl[16];
        sh_f32(x/lc, y/lc, z/lc, Yl);
#pragma unroll
        for (int i = 0; i < 16; ++i) s_Y[t*16+i] = Yl[i];
    }
    // zero the shared message accumulator
    for (int i = t; i < 4*FEAT; i += BLK) s_msg[i] = 0.f;
    __syncthreads();

    // preload this lane's single u-row of x (u = 16*wave + ul); halves of nf
    // row are read by disjoint waves -> total HBM bytes unchanged vs R11
    float xr[16];
    {
        const float* xrow = nf + (size_t)s_src[el4]*FEAT;
        const int u = 16*wave + ul;
        xr[0] = xrow[u];
#pragma unroll
        for (int i = 0; i < 3; ++i) xr[1+i] = xrow[32 + u*3 + i];
#pragma unroll
        for (int i = 0; i < 5; ++i) xr[4+i] = xrow[128 + u*5 + i];
#pragma unroll
        for (int i = 0; i < 7; ++i) xr[9+i] = xrow[288 + u*7 + i];
    }

    do_group<0>(t,lane,el4,ul,bvaddr,avaddr,xr,w3j,Awhi,Awlo,Abhi,Ablo,
                s_Y, s_zp, s_Bhi[wave], s_Blo[wave], s_len, s_msg);
    do_group<1>(t,lane,el4,ul,bvaddr,avaddr,xr,w3j,Awhi,Awlo,Abhi,Ablo,
                s_Y, s_zp, s_Bhi[wave], s_Blo[wave], s_len, s_msg);
    do_group<2>(t,lane,el4,ul,bvaddr,avaddr,xr,w3j,Awhi,Awlo,Abhi,Ablo,
                s_Y, s_zp, s_Bhi[wave], s_Blo[wave], s_len, s_msg);
    do_group<3>(t,lane,el4,ul,bvaddr,avaddr,xr,w3j,Awhi,Awlo,Abhi,Ablo,
                s_Y, s_zp, s_Bhi[wave], s_Blo[wave], s_len, s_msg);
    __syncthreads();

    // single end-of-block coalesced scatter burst (R11 pattern; keeps out L2-resident)
    for (int i = t; i < 4*FEAT; i += BLK) {
        const int elc = i >> 9, m = i & 511;
        atomicAdd(&out[(size_t)s_dst[elc]*FEAT + m], s_msg[i]);
    }
}

extern "C" void kernel_launch(void* const* d_in, const int* in_sizes, int n_in,
                              void* d_out, int out_size, void* d_ws, size_t ws_size,
                              hipStream_t stream) {
    const float* nf   = (const float*)d_in[0];
    const int*   eidx = (const int*)  d_in[1];
    const float* ev   = (const float*)d_in[2];
    const float* ww   = (const float*)d_in[3];
    const float* wb   = (const float*)d_in[4];
    float* out = (float*)d_out;

    float* w3j = (float*)d_ws;                                   // 7500 B
    unsigned short* Awhi = (unsigned short*)((char*)d_ws + 16384);
    unsigned short* Awlo = Awhi + N_PATHS*1024;
    unsigned short* Abhi = Awlo + N_PATHS*1024;
    unsigned short* Ablo = Abhi + N_PATHS*1024;                  // ends at 204800 B

    w3j_setup_kernel<<<N_PATHS + ZERO_BLOCKS, 512, 0, stream>>>(
        ww, wb, w3j, Awhi, Awlo, Abhi, Ablo, out);
    edge_kernel<<<N_EDGES/4, BLK, 0, stream>>>(nf, eidx, ev, w3j, Awhi, Awlo, Abhi, Ablo, out);
}

// Round 9
// 122.080 us; speedup vs baseline: 1.4218x; 1.1932x over previous
//
#include <hip/hip_runtime.h>
#include <math.h>

#define N_PATHS 23
#define HIDDEN  32
#define N_NODES 4096
#define N_EDGES 8192
#define FEAT    512
#define BLK     128   // 2 waves; 4 edges per wave (R11 structure; R20 path-dedup for I$)
#define ZERO_BLOCKS 256

// wave-local LDS phase separator (all prior DS ops complete)
#define WAVE_SYNC() asm volatile("s_waitcnt lgkmcnt(0)" ::: "memory")

typedef __attribute__((ext_vector_type(8)))  short bf16x8;
typedef __attribute__((ext_vector_type(16))) float f32x16;

// ---- compile-time path metadata (PATHS enumeration: l1 outer, l2, l3) ----
constexpr int cL1[N_PATHS] = {0,0,0,0, 1,1,1,1,1,1, 2,2,2,2,2,2,2, 3,3,3,3,3,3};
constexpr int cL2[N_PATHS] = {0,1,2,3, 0,1,1,2,2,3, 0,1,1,2,2,3,3, 0,1,2,2,3,3};
constexpr int cCOFF[N_PATHS]= {0,1,10,35,84,93,102,147,192,297,402,427,472,577,602,727,832,1077,1126,1231,1336,1581,1630};
constexpr int cL3P[N_PATHS] = {0,5,13,21, 1,4,7,11,15,19, 2,6,9,10,14,18,22, 3,8,12,16,17,20};
constexpr int cL3S[5] = {0,4,10,17,23};
constexpr int cOFF3[4] = {0,32,128,288};
__device__ const int CNT_L3[4] = {4,6,7,6};
__device__ const int D_L3[N_PATHS] = {0,1,2,3, 1,0,2,1,3,2, 2,1,3,0,2,1,3, 3,2,1,3,0,2};

// per-edge z offset of path slot pi within its group's batched z buffer
constexpr int zOff(int G, int pi) {
    int off = 0;
    for (int q = cL3S[G]; q < pi; ++q) off += (2*cL1[cL3P[q]]+1)*(2*G+1);
    return off;
}
// max per-edge z total over groups: G3 = 196 -> 4*196 = 784 floats

constexpr int grpN (int G)        { return cL3S[G+1] - cL3S[G]; }
constexpr int pSlot(int G, int i) { return cL3P[cL3S[G] + i]; }
constexpr int zO   (int G, int i) { return zOff(G, cL3S[G] + i); }
// A-pointer offset and z byte offset for slot i of group G (wave-uniform scalars)
constexpr int pOffA(int G, int i) { return pSlot(G,i) * 1024; }
constexpr int zOff4(int G, int i) { return 4 * zO(G,i); }

// ---- 8-point Gauss-Legendre nodes/weights (128-pt rule: exact for degree<=9 SH triple products) ----
__device__ const double GLX8[8] = {
    -0.96028985649753623168, -0.79666647741362673959, -0.52553240991632898582, -0.18343464249564980494,
     0.18343464249564980494,  0.52553240991632898582,  0.79666647741362673959,  0.96028985649753623168};
__device__ const double GLW8[8] = {
     0.10122853629037625915,  0.22238103445337447054,  0.31370664587788728734,  0.36268378337836198297,
     0.36268378337836198297,  0.31370664587788728734,  0.22238103445337447054,  0.10122853629037625915};
// cos/sin(k*pi/8), k=0..15 — exact literals
__device__ const double COSP16[16] = {
  1.0,                     0.92387953251128675613,  0.70710678118654752440,  0.38268343236508977173,
  0.0,                    -0.38268343236508977173, -0.70710678118654752440, -0.92387953251128675613,
 -1.0,                    -0.92387953251128675613, -0.70710678118654752440, -0.38268343236508977173,
  0.0,                     0.38268343236508977173,  0.70710678118654752440,  0.92387953251128675613};
__device__ const double SINP16[16] = {
  0.0,                     0.38268343236508977173,  0.70710678118654752440,  0.92387953251128675613,
  1.0,                     0.92387953251128675613,  0.70710678118654752440,  0.38268343236508977173,
  0.0,                    -0.38268343236508977173, -0.70710678118654752440, -0.92387953251128675613,
 -1.0,                    -0.92387953251128675613, -0.70710678118654752440, -0.38268343236508977173};

__device__ inline void sh_f64(double x, double y, double z, double* Y) {
    const double s3 = 1.7320508075688772935, s5 = 2.2360679774997896964,
                 s7 = 2.6457513110645905905, s15 = 3.8729833462074168852;
    const double c58 = 0.79056941504209483300, c38 = 0.61237243569579452455;
    Y[0] = 1.0;
    Y[1] = s3*x;  Y[2] = s3*y;  Y[3] = s3*z;
    Y[4] = s5*s3*x*z;  Y[5] = s5*s3*x*y;
    Y[6] = s5*(y*y - 0.5*(x*x + z*z));
    Y[7] = s5*s3*y*z;  Y[8] = s5*(s3/2.0)*(z*z - x*x);
    Y[9] = s7*c58*x*(3.0*z*z - x*x);
    Y[10]= s7*s15*x*y*z;
    Y[11]= s7*c38*x*(5.0*y*y - 1.0);
    Y[12]= s7*0.5*y*(5.0*y*y - 3.0);
    Y[13]= s7*c38*z*(5.0*y*y - 1.0);
    Y[14]= s7*(s15/2.0)*y*(z*z - x*x);
    Y[15]= s7*c58*z*(z*z - 3.0*x*x);
}

__device__ inline void sh_f32(float x, float y, float z, float* Y) {
    const float s3 = 1.73205080757f, s5 = 2.23606797750f, s7 = 2.64575131106f, s15 = 3.87298334621f;
    const float c58 = 0.79056941504f, c38 = 0.61237243570f;
    Y[0] = 1.0f;
    Y[1] = s3*x;  Y[2] = s3*y;  Y[3] = s3*z;
    Y[4] = s15*x*z;  Y[5] = s15*x*y;
    Y[6] = s5*(y*y - 0.5f*(x*x + z*z));
    Y[7] = s15*y*z;  Y[8] = s5*(s3*0.5f)*(z*z - x*x);
    Y[9] = s7*c58*x*(3.0f*z*z - x*x);
    Y[10]= s7*s15*x*y*z;
    Y[11]= s7*c38*x*(5.0f*y*y - 1.0f);
    Y[12]= s7*0.5f*y*(5.0f*y*y - 3.0f);
    Y[13]= s7*c38*z*(5.0f*y*y - 1.0f);
    Y[14]= s7*(s15*0.5f)*y*(z*z - x*x);
    Y[15]= s7*c58*z*(z*z - 3.0f*x*x);
}

__device__ inline unsigned short bf16rne(float x) {
    unsigned int u = __float_as_uint(x);
    unsigned int r = (u + 0x7FFFu + ((u >> 16) & 1u)) >> 16;
    return (unsigned short)r;
}
__device__ inline float bf16f(unsigned short h) {
    return __uint_as_float(((unsigned int)h) << 16);
}

// ---- setup: W3J tables (128-pt quadrature) + weight transpose + output zeroing ----
__global__ __launch_bounds__(512) void w3j_setup_kernel(
    const float* __restrict__ ww, const float* __restrict__ wb,
    float* __restrict__ g_w3j,
    unsigned short* __restrict__ Awhi, unsigned short* __restrict__ Awlo,
    unsigned short* __restrict__ Abhi, unsigned short* __restrict__ Ablo,
    float* __restrict__ out) {
    const int t = threadIdx.x;

    if (blockIdx.x >= N_PATHS) {   // zero-blocks
        const int b = blockIdx.x - N_PATHS;
        float4* o4 = (float4*)(out + (size_t)b * (N_NODES*FEAT/ZERO_BLOCKS));
#pragma unroll
        for (int r = 0; r < 4; ++r)
            o4[t + 512*r] = make_float4(0.f,0.f,0.f,0.f);
        return;
    }

    __shared__ float s_Yq[128][17];
    __shared__ float s_wq[128];
    __shared__ float s_part[256];
    __shared__ float red[256];
    __shared__ float s_scale;

    const int p = blockIdx.x;
    const int l1 = cL1[p], l2 = cL2[p];
    const int l3 = D_L3[p];
    const int d2 = 2*l2+1, d3 = 2*l3+1;
    const int csize = (2*l1+1)*d2*d3;
    const double step = 2.0*3.14159265358979323846/16.0;

    // weight transpose to A-layout [p][w][u], bf16 hi/lo split
#pragma unroll
    for (int r = 0; r < 2; ++r) {
        const int idx = t + 512*r;
        const int w = idx >> 5, u = idx & 31;
        const float vw = ww[p*1024 + u*32 + w];
        const float vb = wb[p*1024 + u*32 + w];
        const unsigned short hw = bf16rne(vw);
        const unsigned short hb = bf16rne(vb);
        const int o = p*1024 + w*32 + u;
        Awhi[o] = hw;  Awlo[o] = bf16rne(vw - bf16f(hw));
        Abhi[o] = hb;  Ablo[o] = bf16rne(vb - bf16f(hb));
    }

    // phase A: one quadrature point per thread (first 128 threads)
    if (t < 128) {
        const int iu = t >> 4, ip = t & 15;
        const double u = GLX8[iu];
        const double st = sqrt(fmax(1.0 - u*u, 0.0));
        double Y[16];
        sh_f64(st*COSP16[ip], st*SINP16[ip], u, Y);
#pragma unroll
        for (int i = 0; i < 16; ++i) s_Yq[t][i] = (float)Y[i];
        s_wq[t] = (float)(GLW8[iu] * step);
    }
    __syncthreads();

    // phase B: 4 threads/entry, 32 interleaved points each, shuffle-reduce
    const int entry0 = t >> 2, sub = t & 3;
#pragma unroll
    for (int pass = 0; pass < 2; ++pass) {
        const int entry = entry0 + pass*128;
        float acc = 0.f;
        if (entry < csize) {
            const int i = entry/(d2*d3); const int r = entry - i*(d2*d3);
            const int j = r/d3; const int k = r - j*d3;
            const int ai = l1*l1+i, bi = l2*l2+j, ci = l3*l3+k;
#pragma unroll 4
            for (int it = 0; it < 32; ++it) {
                const int q = it*4 + sub;
                acc = fmaf(s_wq[q] * s_Yq[q][ai] * s_Yq[q][bi], s_Yq[q][ci], acc);
            }
        }
        acc += __shfl_xor(acc, 1);
        acc += __shfl_xor(acc, 2);
        if (sub == 0 && entry < csize) s_part[entry] = acc;
    }
    __syncthreads();

    if (t < 256) { const float v = (t < csize) ? s_part[t] : 0.f; red[t] = v*v; }
    __syncthreads();
    for (int s = 128; s > 0; s >>= 1) {
        if (t < s) red[t] += red[t+s];
        __syncthreads();
    }
    if (t == 0) {
        const float pw = sqrtf((float)(2*l3+1) / ((float)CNT_L3[l3] * (float)HIDDEN));
        s_scale = pw / sqrtf(red[0]);
    }
    __syncthreads();
    if (t < csize) g_w3j[cCOFF[p] + t] = s_part[t] * s_scale;
}

// ---- batched z for one path (no sync): z[el][i][k] into group z buffer ----
template<int G, int P, int ZOFF>
__device__ __forceinline__ void do_zpath(
    int lane, const float* __restrict__ w3j, const float* sY, float* sz)
{
    constexpr int l1 = cL1[P], l2 = cL2[P];
    constexpr int d1 = 2*l1+1, d2 = 2*l2+1, d3 = 2*G+1;
    constexpr int zc = d1*d3;
#pragma unroll
    for (int base = 0; base < 4*zc; base += 64) {
        const int idx = base + lane;
        if (idx < 4*zc) {
            const int elz = idx / zc;          // const-div
            const int r = idx - elz*zc;
            const int i = r / d3, k = r - i*d3;
            const float* Cp = w3j + cCOFF[P] + i*(d2*d3) + k;
            const float* Yp = sY + elz*16 + l2*l2;
            float acc = 0.f;
#pragma unroll
            for (int j = 0; j < d2; ++j) acc = fmaf(Yp[j], Cp[j*d3], acc);
            sz[4*ZOFF + elz*zc + r] = acc;
        }
    }
}

// ---- ONE path body, shapes compile-time, base offsets runtime (R20 dedup unit) ----
// Identical schedule to R11: A loads -> tmp/stage -> lgkmcnt(0) -> B reads + 12 MFMA -> lgkmcnt(0)
template<int G, int D1>
__device__ __forceinline__ void path_body(
    int Poff, int zoff4,                       // wave-uniform: A table offset, z float offset
    int el4, int u0, int bvaddr, int avaddr,
    const float (&xr0)[16], const float (&xr1)[16],
    const unsigned short* __restrict__ Awhi, const unsigned short* __restrict__ Awlo,
    const unsigned short* __restrict__ Abhi, const unsigned short* __restrict__ Ablo,
    const float* sz,
    unsigned short* sbh, unsigned short* sbl,
    f32x16 &Cw, f32x16 &Cb)
{
    constexpr int d3 = 2*G+1;
    constexpr int zc = D1*d3;
    constexpr int l1 = (D1-1)/2;
    constexpr int xo = l1*l1;

    // A-operand loads (global/L2) BEFORE the tmp VALU block hides their latency
    bf16x8 awh[2], awl[2], abh[2], abl[2];
#pragma unroll
    for (int kc = 0; kc < 2; ++kc) {
        awh[kc] = *(const bf16x8*)(Awhi + Poff + avaddr + kc*16);
        awl[kc] = *(const bf16x8*)(Awlo + Poff + avaddr + kc*16);
        abh[kc] = *(const bf16x8*)(Abhi + Poff + avaddr + kc*16);
        abl[kc] = *(const bf16x8*)(Ablo + Poff + avaddr + kc*16);
    }

    // tmp[u][k] = sum_i x[u,i]*z[i,k] for u=2u0,2u0+1; chop-split bf16; packed u32 stores
    {
        const float* zr = sz + zoff4 + el4*zc;
        unsigned short* bh = sbh + (el4*d3)*40 + 2*u0;
        unsigned short* bl = sbl + (el4*d3)*40 + 2*u0;
#pragma unroll
        for (int k = 0; k < d3; ++k) {
            float t0 = 0.f, t1 = 0.f;
#pragma unroll
            for (int i = 0; i < D1; ++i) {
                const float zz = zr[i*d3 + k];
                t0 = fmaf(xr0[xo+i], zz, t0);
                t1 = fmaf(xr1[xo+i], zz, t1);
            }
            const unsigned int b0 = __float_as_uint(t0);
            const unsigned int b1 = __float_as_uint(t1);
            const float l0 = t0 - __uint_as_float(b0 & 0xFFFF0000u);
            const float l1f = t1 - __uint_as_float(b1 & 0xFFFF0000u);
            *(unsigned int*)(bh + k*40) = (b0 >> 16) | (b1 & 0xFFFF0000u);
            *(unsigned int*)(bl + k*40) = (__float_as_uint(l0) >> 16) | (__float_as_uint(l1f) & 0xFFFF0000u);
        }
    }
    WAVE_SYNC();

    // B loads + 12 MFMA (2 K-chunks x 3-pass hi/lo x {w,b}), interleaved dual chains
    __builtin_amdgcn_s_setprio(1);
#pragma unroll
    for (int kc = 0; kc < 2; ++kc) {
        const bf16x8 bh = *(const bf16x8*)(sbh + bvaddr + kc*16);
        const bf16x8 bl = *(const bf16x8*)(sbl + bvaddr + kc*16);
        Cw = __builtin_amdgcn_mfma_f32_32x32x16_bf16(awh[kc], bh, Cw, 0, 0, 0);
        Cb = __builtin_amdgcn_mfma_f32_32x32x16_bf16(abh[kc], bh, Cb, 0, 0, 0);
        Cw = __builtin_amdgcn_mfma_f32_32x32x16_bf16(awh[kc], bl, Cw, 0, 0, 0);
        Cb = __builtin_amdgcn_mfma_f32_32x32x16_bf16(abh[kc], bl, Cb, 0, 0, 0);
        Cw = __builtin_amdgcn_mfma_f32_32x32x16_bf16(awl[kc], bh, Cw, 0, 0, 0);
        Cb = __builtin_amdgcn_mfma_f32_32x32x16_bf16(abl[kc], bh, Cb, 0, 0, 0);
    }
    __builtin_amdgcn_s_setprio(0);
    WAVE_SYNC();  // B reads done before next path's stage overwrites
}

// ---- R20: two same-shape paths share ONE code body (rolled 2-trip loop).
// Offsets are wave-uniform scalars picked via cndmask/s_cselect — shapes stay
// compile-time, so no scratch arrays and no R17-style indexing pathologies.
template<int G, int D1, typename... Args>
__device__ __forceinline__ void run_pair(
    int P0, int Z0, int P1, int Z1,
    int el4, int u0, int bvaddr, int avaddr,
    const float (&xr0)[16], const float (&xr1)[16],
    const unsigned short* __restrict__ Awhi, const unsigned short* __restrict__ Awlo,
    const unsigned short* __restrict__ Abhi, const unsigned short* __restrict__ Ablo,
    const float* sz,
    unsigned short* sbh, unsigned short* sbl,
    f32x16 &Cw, f32x16 &Cb)
{
#pragma unroll 1
    for (int r = 0; r < 2; ++r) {
        path_body<G, D1>(r ? P1 : P0, r ? Z1 : Z0,
                         el4, u0, bvaddr, avaddr, xr0, xr1,
                         Awhi, Awlo, Abhi, Ablo, sz, sbh, sbl, Cw, Cb);
    }
}

// ---- one l3 group: batched z (1 sync), then deduped per-path tmp+MFMA; epilogue into s_msg ----
template<int G>
__device__ __forceinline__ void do_group(
    int lane, int el4, int u0, int bvaddr, int avaddr,
    const float (&xr0)[16], const float (&xr1)[16],
    const float* __restrict__ w3j,
    const unsigned short* __restrict__ Awhi, const unsigned short* __restrict__ Awlo,
    const unsigned short* __restrict__ Abhi, const unsigned short* __restrict__ Ablo,
    const float* sY, float* sz,
    unsigned short* sbh, unsigned short* sbl,
    const float* slen, float* smsg)
{
    constexpr int d3 = 2*G+1;
    constexpr int n = grpN(G);
    f32x16 Cw = (f32x16)(0.f), Cb = (f32x16)(0.f);

    // batched z: all paths of the group, single sync (unchanged from R11)
    do_zpath<G, pSlot(G,0), zO(G,0)>(lane, w3j, sY, sz);
    do_zpath<G, pSlot(G,1), zO(G,1)>(lane, w3j, sY, sz);
    do_zpath<G, pSlot(G,2), zO(G,2)>(lane, w3j, sY, sz);
    do_zpath<G, pSlot(G,3), zO(G,3)>(lane, w3j, sY, sz);
    if constexpr (n > 4) do_zpath<G, pSlot(G,4), zO(G,4)>(lane, w3j, sY, sz);
    if constexpr (n > 5) do_zpath<G, pSlot(G,5), zO(G,5)>(lane, w3j, sY, sz);
    if constexpr (n > 6) do_zpath<G, pSlot(G,6), zO(G,6)>(lane, w3j, sY, sz);
    WAVE_SYNC();

    // path phase, same path ORDER as R11 (slots ascending) — numerics identical.
    // Slots within each group are sorted by d1; equal-d1 slots are consecutive.
    if constexpr (G == 0) {
        // d1: 1,3,5,7 — all distinct
        path_body<0,1>(pOffA(0,0), zOff4(0,0), el4,u0,bvaddr,avaddr,xr0,xr1,Awhi,Awlo,Abhi,Ablo,sz,sbh,sbl,Cw,Cb);
        path_body<0,3>(pOffA(0,1), zOff4(0,1), el4,u0,bvaddr,avaddr,xr0,xr1,Awhi,Awlo,Abhi,Ablo,sz,sbh,sbl,Cw,Cb);
        path_body<0,5>(pOffA(0,2), zOff4(0,2), el4,u0,bvaddr,avaddr,xr0,xr1,Awhi,Awlo,Abhi,Ablo,sz,sbh,sbl,Cw,Cb);
        path_body<0,7>(pOffA(0,3), zOff4(0,3), el4,u0,bvaddr,avaddr,xr0,xr1,Awhi,Awlo,Abhi,Ablo,sz,sbh,sbl,Cw,Cb);
    } else if constexpr (G == 1) {
        // d1: 1, 3,3, 5,5, 7
        path_body<1,1>(pOffA(1,0), zOff4(1,0), el4,u0,bvaddr,avaddr,xr0,xr1,Awhi,Awlo,Abhi,Ablo,sz,sbh,sbl,Cw,Cb);
        run_pair <1,3>(pOffA(1,1), zOff4(1,1), pOffA(1,2), zOff4(1,2), el4,u0,bvaddr,avaddr,xr0,xr1,Awhi,Awlo,Abhi,Ablo,sz,sbh,sbl,Cw,Cb);
        run_pair <1,5>(pOffA(1,3), zOff4(1,3), pOffA(1,4), zOff4(1,4), el4,u0,bvaddr,avaddr,xr0,xr1,Awhi,Awlo,Abhi,Ablo,sz,sbh,sbl,Cw,Cb);
        path_body<1,7>(pOffA(1,5), zOff4(1,5), el4,u0,bvaddr,avaddr,xr0,xr1,Awhi,Awlo,Abhi,Ablo,sz,sbh,sbl,Cw,Cb);
    } else if constexpr (G == 2) {
        // d1: 1, 3,3, 5,5, 7,7
        path_body<2,1>(pOffA(2,0), zOff4(2,0), el4,u0,bvaddr,avaddr,xr0,xr1,Awhi,Awlo,Abhi,Ablo,sz,sbh,sbl,Cw,Cb);
        run_pair <2,3>(pOffA(2,1), zOff4(2,1), pOffA(2,2), zOff4(2,2), el4,u0,bvaddr,avaddr,xr0,xr1,Awhi,Awlo,Abhi,Ablo,sz,sbh,sbl,Cw,Cb);
        run_pair <2,5>(pOffA(2,3), zOff4(2,3), pOffA(2,4), zOff4(2,4), el4,u0,bvaddr,avaddr,xr0,xr1,Awhi,Awlo,Abhi,Ablo,sz,sbh,sbl,Cw,Cb);
        run_pair <2,7>(pOffA(2,5), zOff4(2,5), pOffA(2,6), zOff4(2,6), el4,u0,bvaddr,avaddr,xr0,xr1,Awhi,Awlo,Abhi,Ablo,sz,sbh,sbl,Cw,Cb);
    } else {
        // G == 3; d1: 1, 3, 5,5, 7,7
        path_body<3,1>(pOffA(3,0), zOff4(3,0), el4,u0,bvaddr,avaddr,xr0,xr1,Awhi,Awlo,Abhi,Ablo,sz,sbh,sbl,Cw,Cb);
        path_body<3,3>(pOffA(3,1), zOff4(3,1), el4,u0,bvaddr,avaddr,xr0,xr1,Awhi,Awlo,Abhi,Ablo,sz,sbh,sbl,Cw,Cb);
        run_pair <3,5>(pOffA(3,2), zOff4(3,2), pOffA(3,3), zOff4(3,3), el4,u0,bvaddr,avaddr,xr0,xr1,Awhi,Awlo,Abhi,Ablo,sz,sbh,sbl,Cw,Cb);
        run_pair <3,7>(pOffA(3,4), zOff4(3,4), pOffA(3,5), zOff4(3,5), el4,u0,bvaddr,avaddr,xr0,xr1,Awhi,Awlo,Abhi,Ablo,sz,sbh,sbl,Cw,Cb);
    }

    // epilogue: msg = len*Cw + Cb
    // C/D layout (verified m74/m101): col=lane&31, row=(reg&3)+8*(reg>>2)+4*(lane>>5)
    const int col = lane & 31;
    if (col < 4*d3) {
        const int elc = col / d3, k = col - elc*d3;   // const-div
        const float len = slen[elc];
        float* mp = smsg + elc*FEAT + cOFF3[G] + k;
#pragma unroll
        for (int reg = 0; reg < 16; ++reg) {
            const int w = (reg & 3) + 8*(reg >> 2) + 4*(lane >> 5);
            mp[w*d3] = fmaf(len, Cw[reg], Cb[reg]);
        }
    }
}

// ---- main: 2 waves/block, 4 edges/wave, 32x32x16 MFMA (R11 structure + R20 dedup) ----
__global__ __launch_bounds__(BLK) void edge_kernel(
    const float* __restrict__ nf,
    const int*   __restrict__ eidx,
    const float* __restrict__ ev,
    const float* __restrict__ w3j,
    const unsigned short* __restrict__ Awhi,
    const unsigned short* __restrict__ Awlo,
    const unsigned short* __restrict__ Abhi,
    const unsigned short* __restrict__ Ablo,
    float*       __restrict__ out)
{
    __shared__ float s_zp[2][784];       // batched per-group z (max G3: 4*196)
    __shared__ float s_Y[2][64];
    __shared__ float s_len[2][4];
    __shared__ int   s_src[2][4];
    __shared__ int   s_dst[2][4];
    __shared__ __align__(16) unsigned short s_Bhi[2][1280];  // [col(32)][u(32)+pad8]
    __shared__ __align__(16) unsigned short s_Blo[2][1280];
    __shared__ float s_msg[2][4*FEAT];

    const int t    = threadIdx.x;
    const int wave = t >> 6;
    const int lane = t & 63;
    const int el4  = lane >> 4;      // tmp-phase edge (4 per wave)
    const int u0   = lane & 15;      // tmp-phase u-pair index
    const int e0   = blockIdx.x * 8 + wave*4;
    const int bvaddr = (lane & 31)*40 + (lane >> 5)*8;   // B: n=lane&31, k0=(lane>>5)*8
    const int avaddr = (lane & 31)*32 + (lane >> 5)*8;   // A: m=lane&31, k0=(lane>>5)*8

    if (lane < 4) {
        const int e = e0 + lane;
        s_src[wave][lane] = eidx[e];
        s_dst[wave][lane] = eidx[N_EDGES + e];
        const float x = ev[e*3+0], y = ev[e*3+1], z = ev[e*3+2];
        const float len = sqrtf(x*x + y*y + z*z);
        const float lc = fmaxf(len, 1e-8f);
        s_len[wave][lane] = lc;
        float Yl[16];
        sh_f32(x/lc, y/lc, z/lc, Yl);
#pragma unroll
        for (int i = 0; i < 16; ++i) s_Y[wave][lane*16+i] = Yl[i];
    }
    WAVE_SYNC();

    // preload this lane's 2 u-rows of x (u = 2u0, 2u0+1) into registers
    float xr0[16], xr1[16];
    {
        const float* xrow = nf + (size_t)s_src[wave][el4]*FEAT;
        const int ua = 2*u0, ub = 2*u0 + 1;
        xr0[0] = xrow[ua];                 xr1[0] = xrow[ub];
#pragma unroll
        for (int i = 0; i < 3; ++i) { xr0[1+i] = xrow[32 + ua*3 + i];  xr1[1+i] = xrow[32 + ub*3 + i]; }
#pragma unroll
        for (int i = 0; i < 5; ++i) { xr0[4+i] = xrow[128 + ua*5 + i]; xr1[4+i] = xrow[128 + ub*5 + i]; }
#pragma unroll
        for (int i = 0; i < 7; ++i) { xr0[9+i] = xrow[288 + ua*7 + i]; xr1[9+i] = xrow[288 + ub*7 + i]; }
    }

    do_group<0>(lane,el4,u0,bvaddr,avaddr,xr0,xr1,w3j,Awhi,Awlo,Abhi,Ablo,
                s_Y[wave], s_zp[wave], s_Bhi[wave], s_Blo[wave], s_len[wave], s_msg[wave]);
    do_group<1>(lane,el4,u0,bvaddr,avaddr,xr0,xr1,w3j,Awhi,Awlo,Abhi,Ablo,
                s_Y[wave], s_zp[wave], s_Bhi[wave], s_Blo[wave], s_len[wave], s_msg[wave]);
    do_group<2>(lane,el4,u0,bvaddr,avaddr,xr0,xr1,w3j,Awhi,Awlo,Abhi,Ablo,
                s_Y[wave], s_zp[wave], s_Bhi[wave], s_Blo[wave], s_len[wave], s_msg[wave]);
    do_group<3>(lane,el4,u0,bvaddr,avaddr,xr0,xr1,w3j,Awhi,Awlo,Abhi,Ablo,
                s_Y[wave], s_zp[wave], s_Bhi[wave], s_Blo[wave], s_len[wave], s_msg[wave]);
    WAVE_SYNC();

    // wave-local coalesced scatter: 4 edges x 512 (R11 actor pattern)
    for (int i = lane; i < 4*FEAT; i += 64) {
        const int elc = i >> 9, m = i & 511;
        atomicAdd(&out[(size_t)s_dst[wave][elc]*FEAT + m], s_msg[wave][i]);
    }
}

extern "C" void kernel_launch(void* const* d_in, const int* in_sizes, int n_in,
                              void* d_out, int out_size, void* d_ws, size_t ws_size,
                              hipStream_t stream) {
    const float* nf   = (const float*)d_in[0];
    const int*   eidx = (const int*)  d_in[1];
    const float* ev   = (const float*)d_in[2];
    const float* ww   = (const float*)d_in[3];
    const float* wb   = (const float*)d_in[4];
    float* out = (float*)d_out;

    float* w3j = (float*)d_ws;                                   // 7500 B
    unsigned short* Awhi = (unsigned short*)((char*)d_ws + 16384);
    unsigned short* Awlo = Awhi + N_PATHS*1024;
    unsigned short* Abhi = Awlo + N_PATHS*1024;
    unsigned short* Ablo = Abhi + N_PATHS*1024;                  // ends at 204800 B

    w3j_setup_kernel<<<N_PATHS + ZERO_BLOCKS, 512, 0, stream>>>(
        ww, wb, w3j, Awhi, Awlo, Abhi, Ablo, out);
    edge_kernel<<<N_EDGES/8, BLK, 0, stream>>>(nf, eidx, ev, w3j, Awhi, Awlo, Abhi, Ablo, out);
}

// Round 11
// 121.026 us; speedup vs baseline: 1.4342x; 1.0087x over previous
//
#include <hip/hip_runtime.h>
#include <math.h>

#define N_PATHS 23
#define HIDDEN  32
#define N_NODES 4096
#define N_EDGES 8192
#define FEAT    512
#define BLK     128   // 2 waves; 4 edges per wave (R11/R20 structure; R22 soft fences)
#define ZERO_BLOCKS 256

// R22: COMPILER-ONLY phase separator. Per-wave DS ops execute in order on the
// LDS pipe (HW-verified: R15 passed with no fences at all), so RAW/WAR through
// wave-local LDS needs no hardware wait; the compiler inserts counted
// lgkmcnt(N) before true data uses. The "memory" clobber pins instruction
// placement exactly as R11's s_waitcnt did — without stalling the wave.
#define WAVE_SYNC() asm volatile("" ::: "memory")

typedef __attribute__((ext_vector_type(8)))  short bf16x8;
typedef __attribute__((ext_vector_type(16))) float f32x16;

// ---- compile-time path metadata (PATHS enumeration: l1 outer, l2, l3) ----
constexpr int cL1[N_PATHS] = {0,0,0,0, 1,1,1,1,1,1, 2,2,2,2,2,2,2, 3,3,3,3,3,3};
constexpr int cL2[N_PATHS] = {0,1,2,3, 0,1,1,2,2,3, 0,1,1,2,2,3,3, 0,1,2,2,3,3};
constexpr int cCOFF[N_PATHS]= {0,1,10,35,84,93,102,147,192,297,402,427,472,577,602,727,832,1077,1126,1231,1336,1581,1630};
constexpr int cL3P[N_PATHS] = {0,5,13,21, 1,4,7,11,15,19, 2,6,9,10,14,18,22, 3,8,12,16,17,20};
constexpr int cL3S[5] = {0,4,10,17,23};
constexpr int cOFF3[4] = {0,32,128,288};
__device__ const int CNT_L3[4] = {4,6,7,6};
__device__ const int D_L3[N_PATHS] = {0,1,2,3, 1,0,2,1,3,2, 2,1,3,0,2,1,3, 3,2,1,3,0,2};

// per-edge z offset of path slot pi within its group's batched z buffer
constexpr int zOff(int G, int pi) {
    int off = 0;
    for (int q = cL3S[G]; q < pi; ++q) off += (2*cL1[cL3P[q]]+1)*(2*G+1);
    return off;
}
// max per-edge z total over groups: G3 = 196 -> 4*196 = 784 floats

constexpr int grpN (int G)        { return cL3S[G+1] - cL3S[G]; }
constexpr int pSlot(int G, int i) { return cL3P[cL3S[G] + i]; }
constexpr int zO   (int G, int i) { return zOff(G, cL3S[G] + i); }
// A-pointer offset and z float offset for slot i of group G (wave-uniform scalars)
constexpr int pOffA(int G, int i) { return pSlot(G,i) * 1024; }
constexpr int zOff4(int G, int i) { return 4 * zO(G,i); }

// ---- 8-point Gauss-Legendre nodes/weights (128-pt rule: exact for degree<=9 SH triple products) ----
__device__ const double GLX8[8] = {
    -0.96028985649753623168, -0.79666647741362673959, -0.52553240991632898582, -0.18343464249564980494,
     0.18343464249564980494,  0.52553240991632898582,  0.79666647741362673959,  0.96028985649753623168};
__device__ const double GLW8[8] = {
     0.10122853629037625915,  0.22238103445337447054,  0.31370664587788728734,  0.36268378337836198297,
     0.36268378337836198297,  0.31370664587788728734,  0.22238103445337447054,  0.10122853629037625915};
// cos/sin(k*pi/8), k=0..15 — exact literals
__device__ const double COSP16[16] = {
  1.0,                     0.92387953251128675613,  0.70710678118654752440,  0.38268343236508977173,
  0.0,                    -0.38268343236508977173, -0.70710678118654752440, -0.92387953251128675613,
 -1.0,                    -0.92387953251128675613, -0.70710678118654752440, -0.38268343236508977173,
  0.0,                     0.38268343236508977173,  0.70710678118654752440,  0.92387953251128675613};
__device__ const double SINP16[16] = {
  0.0,                     0.38268343236508977173,  0.70710678118654752440,  0.92387953251128675613,
  1.0,                     0.92387953251128675613,  0.70710678118654752440,  0.38268343236508977173,
  0.0,                    -0.38268343236508977173, -0.70710678118654752440, -0.92387953251128675613,
 -1.0,                    -0.92387953251128675613, -0.70710678118654752440, -0.38268343236508977173};

__device__ inline void sh_f64(double x, double y, double z, double* Y) {
    const double s3 = 1.7320508075688772935, s5 = 2.2360679774997896964,
                 s7 = 2.6457513110645905905, s15 = 3.8729833462074168852;
    const double c58 = 0.79056941504209483300, c38 = 0.61237243569579452455;
    Y[0] = 1.0;
    Y[1] = s3*x;  Y[2] = s3*y;  Y[3] = s3*z;
    Y[4] = s5*s3*x*z;  Y[5] = s5*s3*x*y;
    Y[6] = s5*(y*y - 0.5*(x*x + z*z));
    Y[7] = s5*s3*y*z;  Y[8] = s5*(s3/2.0)*(z*z - x*x);
    Y[9] = s7*c58*x*(3.0*z*z - x*x);
    Y[10]= s7*s15*x*y*z;
    Y[11]= s7*c38*x*(5.0*y*y - 1.0);
    Y[12]= s7*0.5*y*(5.0*y*y - 3.0);
    Y[13]= s7*c38*z*(5.0*y*y - 1.0);
    Y[14]= s7*(s15/2.0)*y*(z*z - x*x);
    Y[15]= s7*c58*z*(z*z - 3.0*x*x);
}

__device__ inline void sh_f32(float x, float y, float z, float* Y) {
    const float s3 = 1.73205080757f, s5 = 2.23606797750f, s7 = 2.64575131106f, s15 = 3.87298334621f;
    const float c58 = 0.79056941504f, c38 = 0.61237243570f;
    Y[0] = 1.0f;
    Y[1] = s3*x;  Y[2] = s3*y;  Y[3] = s3*z;
    Y[4] = s15*x*z;  Y[5] = s15*x*y;
    Y[6] = s5*(y*y - 0.5f*(x*x + z*z));
    Y[7] = s15*y*z;  Y[8] = s5*(s3*0.5f)*(z*z - x*x);
    Y[9] = s7*c58*x*(3.0f*z*z - x*x);
    Y[10]= s7*s15*x*y*z;
    Y[11]= s7*c38*x*(5.0f*y*y - 1.0f);
    Y[12]= s7*0.5f*y*(5.0f*y*y - 3.0f);
    Y[13]= s7*c38*z*(5.0f*y*y - 1.0f);
    Y[14]= s7*(s15*0.5f)*y*(z*z - x*x);
    Y[15]= s7*c58*z*(z*z - 3.0f*x*x);
}

__device__ inline unsigned short bf16rne(float x) {
    unsigned int u = __float_as_uint(x);
    unsigned int r = (u + 0x7FFFu + ((u >> 16) & 1u)) >> 16;
    return (unsigned short)r;
}
__device__ inline float bf16f(unsigned short h) {
    return __uint_as_float(((unsigned int)h) << 16);
}

// ---- setup: W3J tables (128-pt quadrature) + weight transpose + output zeroing ----
__global__ __launch_bounds__(512) void w3j_setup_kernel(
    const float* __restrict__ ww, const float* __restrict__ wb,
    float* __restrict__ g_w3j,
    unsigned short* __restrict__ Awhi, unsigned short* __restrict__ Awlo,
    unsigned short* __restrict__ Abhi, unsigned short* __restrict__ Ablo,
    float* __restrict__ out) {
    const int t = threadIdx.x;

    if (blockIdx.x >= N_PATHS) {   // zero-blocks
        const int b = blockIdx.x - N_PATHS;
        float4* o4 = (float4*)(out + (size_t)b * (N_NODES*FEAT/ZERO_BLOCKS));
#pragma unroll
        for (int r = 0; r < 4; ++r)
            o4[t + 512*r] = make_float4(0.f,0.f,0.f,0.f);
        return;
    }

    __shared__ float s_Yq[128][17];
    __shared__ float s_wq[128];
    __shared__ float s_part[256];
    __shared__ float red[256];
    __shared__ float s_scale;

    const int p = blockIdx.x;
    const int l1 = cL1[p], l2 = cL2[p];
    const int l3 = D_L3[p];
    const int d2 = 2*l2+1, d3 = 2*l3+1;
    const int csize = (2*l1+1)*d2*d3;
    const double step = 2.0*3.14159265358979323846/16.0;

    // weight transpose to A-layout [p][w][u], bf16 hi/lo split
#pragma unroll
    for (int r = 0; r < 2; ++r) {
        const int idx = t + 512*r;
        const int w = idx >> 5, u = idx & 31;
        const float vw = ww[p*1024 + u*32 + w];
        const float vb = wb[p*1024 + u*32 + w];
        const unsigned short hw = bf16rne(vw);
        const unsigned short hb = bf16rne(vb);
        const int o = p*1024 + w*32 + u;
        Awhi[o] = hw;  Awlo[o] = bf16rne(vw - bf16f(hw));
        Abhi[o] = hb;  Ablo[o] = bf16rne(vb - bf16f(hb));
    }

    // phase A: one quadrature point per thread (first 128 threads)
    if (t < 128) {
        const int iu = t >> 4, ip = t & 15;
        const double u = GLX8[iu];
        const double st = sqrt(fmax(1.0 - u*u, 0.0));
        double Y[16];
        sh_f64(st*COSP16[ip], st*SINP16[ip], u, Y);
#pragma unroll
        for (int i = 0; i < 16; ++i) s_Yq[t][i] = (float)Y[i];
        s_wq[t] = (float)(GLW8[iu] * step);
    }
    __syncthreads();

    // phase B: 4 threads/entry, 32 interleaved points each, shuffle-reduce
    const int entry0 = t >> 2, sub = t & 3;
#pragma unroll
    for (int pass = 0; pass < 2; ++pass) {
        const int entry = entry0 + pass*128;
        float acc = 0.f;
        if (entry < csize) {
            const int i = entry/(d2*d3); const int r = entry - i*(d2*d3);
            const int j = r/d3; const int k = r - j*d3;
            const int ai = l1*l1+i, bi = l2*l2+j, ci = l3*l3+k;
#pragma unroll 4
            for (int it = 0; it < 32; ++it) {
                const int q = it*4 + sub;
                acc = fmaf(s_wq[q] * s_Yq[q][ai] * s_Yq[q][bi], s_Yq[q][ci], acc);
            }
        }
        acc += __shfl_xor(acc, 1);
        acc += __shfl_xor(acc, 2);
        if (sub == 0 && entry < csize) s_part[entry] = acc;
    }
    __syncthreads();

    if (t < 256) { const float v = (t < csize) ? s_part[t] : 0.f; red[t] = v*v; }
    __syncthreads();
    for (int s = 128; s > 0; s >>= 1) {
        if (t < s) red[t] += red[t+s];
        __syncthreads();
    }
    if (t == 0) {
        const float pw = sqrtf((float)(2*l3+1) / ((float)CNT_L3[l3] * (float)HIDDEN));
        s_scale = pw / sqrtf(red[0]);
    }
    __syncthreads();
    if (t < csize) g_w3j[cCOFF[p] + t] = s_part[t] * s_scale;
}

// ---- batched z for one path (no sync): z[el][i][k] into group z buffer ----
template<int G, int P, int ZOFF>
__device__ __forceinline__ void do_zpath(
    int lane, const float* __restrict__ w3j, const float* sY, float* sz)
{
    constexpr int l1 = cL1[P], l2 = cL2[P];
    constexpr int d1 = 2*l1+1, d2 = 2*l2+1, d3 = 2*G+1;
    constexpr int zc = d1*d3;
#pragma unroll
    for (int base = 0; base < 4*zc; base += 64) {
        const int idx = base + lane;
        if (idx < 4*zc) {
            const int elz = idx / zc;          // const-div
            const int r = idx - elz*zc;
            const int i = r / d3, k = r - i*d3;
            const float* Cp = w3j + cCOFF[P] + i*(d2*d3) + k;
            const float* Yp = sY + elz*16 + l2*l2;
            float acc = 0.f;
#pragma unroll
            for (int j = 0; j < d2; ++j) acc = fmaf(Yp[j], Cp[j*d3], acc);
            sz[4*ZOFF + elz*zc + r] = acc;
        }
    }
}

// ---- ONE path body, shapes compile-time, base offsets runtime (R20 dedup unit) ----
// Schedule = R11; fences are compiler-only (R22): per-wave in-order DS handles the
// stage-write -> B-read RAW and the B-read -> next-stage WAR without HW drains.
template<int G, int D1>
__device__ __forceinline__ void path_body(
    int Poff, int zoff4,                       // wave-uniform: A table offset, z float offset
    int el4, int u0, int bvaddr, int avaddr,
    const float (&xr0)[16], const float (&xr1)[16],
    const unsigned short* __restrict__ Awhi, const unsigned short* __restrict__ Awlo,
    const unsigned short* __restrict__ Abhi, const unsigned short* __restrict__ Ablo,
    const float* sz,
    unsigned short* sbh, unsigned short* sbl,
    f32x16 &Cw, f32x16 &Cb)
{
    constexpr int d3 = 2*G+1;
    constexpr int zc = D1*d3;
    constexpr int l1 = (D1-1)/2;
    constexpr int xo = l1*l1;

    // A-operand loads (global/L2) BEFORE the tmp VALU block hides their latency
    bf16x8 awh[2], awl[2], abh[2], abl[2];
#pragma unroll
    for (int kc = 0; kc < 2; ++kc) {
        awh[kc] = *(const bf16x8*)(Awhi + Poff + avaddr + kc*16);
        awl[kc] = *(const bf16x8*)(Awlo + Poff + avaddr + kc*16);
        abh[kc] = *(const bf16x8*)(Abhi + Poff + avaddr + kc*16);
        abl[kc] = *(const bf16x8*)(Ablo + Poff + avaddr + kc*16);
    }

    // tmp[u][k] = sum_i x[u,i]*z[i,k] for u=2u0,2u0+1; chop-split bf16; packed u32 stores
    {
        const float* zr = sz + zoff4 + el4*zc;
        unsigned short* bh = sbh + (el4*d3)*40 + 2*u0;
        unsigned short* bl = sbl + (el4*d3)*40 + 2*u0;
#pragma unroll
        for (int k = 0; k < d3; ++k) {
            float t0 = 0.f, t1 = 0.f;
#pragma unroll
            for (int i = 0; i < D1; ++i) {
                const float zz = zr[i*d3 + k];
                t0 = fmaf(xr0[xo+i], zz, t0);
                t1 = fmaf(xr1[xo+i], zz, t1);
            }
            const unsigned int b0 = __float_as_uint(t0);
            const unsigned int b1 = __float_as_uint(t1);
            const float l0 = t0 - __uint_as_float(b0 & 0xFFFF0000u);
            const float l1f = t1 - __uint_as_float(b1 & 0xFFFF0000u);
            *(unsigned int*)(bh + k*40) = (b0 >> 16) | (b1 & 0xFFFF0000u);
            *(unsigned int*)(bl + k*40) = (__float_as_uint(l0) >> 16) | (__float_as_uint(l1f) & 0xFFFF0000u);
        }
    }
    WAVE_SYNC();   // placement fence only: stores stay before reads (in-order DS does the rest)

    // B loads + 12 MFMA (2 K-chunks x 3-pass hi/lo x {w,b}), interleaved dual chains
    __builtin_amdgcn_s_setprio(1);
#pragma unroll
    for (int kc = 0; kc < 2; ++kc) {
        const bf16x8 bh = *(const bf16x8*)(sbh + bvaddr + kc*16);
        const bf16x8 bl = *(const bf16x8*)(sbl + bvaddr + kc*16);
        Cw = __builtin_amdgcn_mfma_f32_32x32x16_bf16(awh[kc], bh, Cw, 0, 0, 0);
        Cb = __builtin_amdgcn_mfma_f32_32x32x16_bf16(abh[kc], bh, Cb, 0, 0, 0);
        Cw = __builtin_amdgcn_mfma_f32_32x32x16_bf16(awh[kc], bl, Cw, 0, 0, 0);
        Cb = __builtin_amdgcn_mfma_f32_32x32x16_bf16(abh[kc], bl, Cb, 0, 0, 0);
        Cw = __builtin_amdgcn_mfma_f32_32x32x16_bf16(awl[kc], bh, Cw, 0, 0, 0);
        Cb = __builtin_amdgcn_mfma_f32_32x32x16_bf16(abl[kc], bh, Cb, 0, 0, 0);
    }
    __builtin_amdgcn_s_setprio(0);
    WAVE_SYNC();   // placement fence: next path's stage stores ordered after these reads
}

// ---- R20: two same-shape paths share ONE code body (rolled 2-trip loop) ----
template<int G, int D1>
__device__ __forceinline__ void run_pair(
    int P0, int Z0, int P1, int Z1,
    int el4, int u0, int bvaddr, int avaddr,
    const float (&xr0)[16], const float (&xr1)[16],
    const unsigned short* __restrict__ Awhi, const unsigned short* __restrict__ Awlo,
    const unsigned short* __restrict__ Abhi, const unsigned short* __restrict__ Ablo,
    const float* sz,
    unsigned short* sbh, unsigned short* sbl,
    f32x16 &Cw, f32x16 &Cb)
{
#pragma unroll 1
    for (int r = 0; r < 2; ++r) {
        path_body<G, D1>(r ? P1 : P0, r ? Z1 : Z0,
                         el4, u0, bvaddr, avaddr, xr0, xr1,
                         Awhi, Awlo, Abhi, Ablo, sz, sbh, sbl, Cw, Cb);
    }
}

// ---- one l3 group: batched z, then deduped per-path tmp+MFMA; epilogue into s_msg ----
template<int G>
__device__ __forceinline__ void do_group(
    int lane, int el4, int u0, int bvaddr, int avaddr,
    const float (&xr0)[16], const float (&xr1)[16],
    const float* __restrict__ w3j,
    const unsigned short* __restrict__ Awhi, const unsigned short* __restrict__ Awlo,
    const unsigned short* __restrict__ Abhi, const unsigned short* __restrict__ Ablo,
    const float* sY, float* sz,
    unsigned short* sbh, unsigned short* sbl,
    const float* slen, float* smsg)
{
    constexpr int d3 = 2*G+1;
    constexpr int n = grpN(G);
    f32x16 Cw = (f32x16)(0.f), Cb = (f32x16)(0.f);

    // batched z: all paths of the group (z writes ordered before z reads by in-order DS)
    do_zpath<G, pSlot(G,0), zO(G,0)>(lane, w3j, sY, sz);
    do_zpath<G, pSlot(G,1), zO(G,1)>(lane, w3j, sY, sz);
    do_zpath<G, pSlot(G,2), zO(G,2)>(lane, w3j, sY, sz);
    do_zpath<G, pSlot(G,3), zO(G,3)>(lane, w3j, sY, sz);
    if constexpr (n > 4) do_zpath<G, pSlot(G,4), zO(G,4)>(lane, w3j, sY, sz);
    if constexpr (n > 5) do_zpath<G, pSlot(G,5), zO(G,5)>(lane, w3j, sY, sz);
    if constexpr (n > 6) do_zpath<G, pSlot(G,6), zO(G,6)>(lane, w3j, sY, sz);
    WAVE_SYNC();

    // path phase, same path ORDER as R11 (slots ascending) — numerics identical.
    if constexpr (G == 0) {
        path_body<0,1>(pOffA(0,0), zOff4(0,0), el4,u0,bvaddr,avaddr,xr0,xr1,Awhi,Awlo,Abhi,Ablo,sz,sbh,sbl,Cw,Cb);
        path_body<0,3>(pOffA(0,1), zOff4(0,1), el4,u0,bvaddr,avaddr,xr0,xr1,Awhi,Awlo,Abhi,Ablo,sz,sbh,sbl,Cw,Cb);
        path_body<0,5>(pOffA(0,2), zOff4(0,2), el4,u0,bvaddr,avaddr,xr0,xr1,Awhi,Awlo,Abhi,Ablo,sz,sbh,sbl,Cw,Cb);
        path_body<0,7>(pOffA(0,3), zOff4(0,3), el4,u0,bvaddr,avaddr,xr0,xr1,Awhi,Awlo,Abhi,Ablo,sz,sbh,sbl,Cw,Cb);
    } else if constexpr (G == 1) {
        path_body<1,1>(pOffA(1,0), zOff4(1,0), el4,u0,bvaddr,avaddr,xr0,xr1,Awhi,Awlo,Abhi,Ablo,sz,sbh,sbl,Cw,Cb);
        run_pair <1,3>(pOffA(1,1), zOff4(1,1), pOffA(1,2), zOff4(1,2), el4,u0,bvaddr,avaddr,xr0,xr1,Awhi,Awlo,Abhi,Ablo,sz,sbh,sbl,Cw,Cb);
        run_pair <1,5>(pOffA(1,3), zOff4(1,3), pOffA(1,4), zOff4(1,4), el4,u0,bvaddr,avaddr,xr0,xr1,Awhi,Awlo,Abhi,Ablo,sz,sbh,sbl,Cw,Cb);
        path_body<1,7>(pOffA(1,5), zOff4(1,5), el4,u0,bvaddr,avaddr,xr0,xr1,Awhi,Awlo,Abhi,Ablo,sz,sbh,sbl,Cw,Cb);
    } else if constexpr (G == 2) {
        path_body<2,1>(pOffA(2,0), zOff4(2,0), el4,u0,bvaddr,avaddr,xr0,xr1,Awhi,Awlo,Abhi,Ablo,sz,sbh,sbl,Cw,Cb);
        run_pair <2,3>(pOffA(2,1), zOff4(2,1), pOffA(2,2), zOff4(2,2), el4,u0,bvaddr,avaddr,xr0,xr1,Awhi,Awlo,Abhi,Ablo,sz,sbh,sbl,Cw,Cb);
        run_pair <2,5>(pOffA(2,3), zOff4(2,3), pOffA(2,4), zOff4(2,4), el4,u0,bvaddr,avaddr,xr0,xr1,Awhi,Awlo,Abhi,Ablo,sz,sbh,sbl,Cw,Cb);
        run_pair <2,7>(pOffA(2,5), zOff4(2,5), pOffA(2,6), zOff4(2,6), el4,u0,bvaddr,avaddr,xr0,xr1,Awhi,Awlo,Abhi,Ablo,sz,sbh,sbl,Cw,Cb);
    } else {
        path_body<3,1>(pOffA(3,0), zOff4(3,0), el4,u0,bvaddr,avaddr,xr0,xr1,Awhi,Awlo,Abhi,Ablo,sz,sbh,sbl,Cw,Cb);
        path_body<3,3>(pOffA(3,1), zOff4(3,1), el4,u0,bvaddr,avaddr,xr0,xr1,Awhi,Awlo,Abhi,Ablo,sz,sbh,sbl,Cw,Cb);
        run_pair <3,5>(pOffA(3,2), zOff4(3,2), pOffA(3,3), zOff4(3,3), el4,u0,bvaddr,avaddr,xr0,xr1,Awhi,Awlo,Abhi,Ablo,sz,sbh,sbl,Cw,Cb);
        run_pair <3,7>(pOffA(3,4), zOff4(3,4), pOffA(3,5), zOff4(3,5), el4,u0,bvaddr,avaddr,xr0,xr1,Awhi,Awlo,Abhi,Ablo,sz,sbh,sbl,Cw,Cb);
    }

    // epilogue: msg = len*Cw + Cb
    // C/D layout (verified m74/m101): col=lane&31, row=(reg&3)+8*(reg>>2)+4*(lane>>5)
    const int col = lane & 31;
    if (col < 4*d3) {
        const int elc = col / d3, k = col - elc*d3;   // const-div
        const float len = slen[elc];
        float* mp = smsg + elc*FEAT + cOFF3[G] + k;
#pragma unroll
        for (int reg = 0; reg < 16; ++reg) {
            const int w = (reg & 3) + 8*(reg >> 2) + 4*(lane >> 5);
            mp[w*d3] = fmaf(len, Cw[reg], Cb[reg]);
        }
    }
}

// ---- main: 2 waves/block, 4 edges/wave, 32x32x16 MFMA (R20 + R22 soft fences) ----
__global__ __launch_bounds__(BLK) void edge_kernel(
    const float* __restrict__ nf,
    const int*   __restrict__ eidx,
    const float* __restrict__ ev,
    const float* __restrict__ w3j,
    const unsigned short* __restrict__ Awhi,
    const unsigned short* __restrict__ Awlo,
    const unsigned short* __restrict__ Abhi,
    const unsigned short* __restrict__ Ablo,
    float*       __restrict__ out)
{
    __shared__ float s_zp[2][784];       // batched per-group z (max G3: 4*196)
    __shared__ float s_Y[2][64];
    __shared__ float s_len[2][4];
    __shared__ int   s_src[2][4];
    __shared__ int   s_dst[2][4];
    __shared__ __align__(16) unsigned short s_Bhi[2][1280];  // [col(32)][u(32)+pad8]
    __shared__ __align__(16) unsigned short s_Blo[2][1280];
    __shared__ float s_msg[2][4*FEAT];

    const int t    = threadIdx.x;
    const int wave = t >> 6;
    const int lane = t & 63;
    const int el4  = lane >> 4;      // tmp-phase edge (4 per wave)
    const int u0   = lane & 15;      // tmp-phase u-pair index
    const int e0   = blockIdx.x * 8 + wave*4;
    const int bvaddr = (lane & 31)*40 + (lane >> 5)*8;   // B: n=lane&31, k0=(lane>>5)*8
    const int avaddr = (lane & 31)*32 + (lane >> 5)*8;   // A: m=lane&31, k0=(lane>>5)*8

    if (lane < 4) {
        const int e = e0 + lane;
        s_src[wave][lane] = eidx[e];
        s_dst[wave][lane] = eidx[N_EDGES + e];
        const float x = ev[e*3+0], y = ev[e*3+1], z = ev[e*3+2];
        const float len = sqrtf(x*x + y*y + z*z);
        const float lc = fmaxf(len, 1e-8f);
        s_len[wave][lane] = lc;
        float Yl[16];
        sh_f32(x/lc, y/lc, z/lc, Yl);
#pragma unroll
        for (int i = 0; i < 16; ++i) s_Y[wave][lane*16+i] = Yl[i];
    }
    WAVE_SYNC();

    // preload this lane's 2 u-rows of x (u = 2u0, 2u0+1) into registers
    float xr0[16], xr1[16];
    {
        const float* xrow = nf + (size_t)s_src[wave][el4]*FEAT;
        const int ua = 2*u0, ub = 2*u0 + 1;
        xr0[0] = xrow[ua];                 xr1[0] = xrow[ub];
#pragma unroll
        for (int i = 0; i < 3; ++i) { xr0[1+i] = xrow[32 + ua*3 + i];  xr1[1+i] = xrow[32 + ub*3 + i]; }
#pragma unroll
        for (int i = 0; i < 5; ++i) { xr0[4+i] = xrow[128 + ua*5 + i]; xr1[4+i] = xrow[128 + ub*5 + i]; }
#pragma unroll
        for (int i = 0; i < 7; ++i) { xr0[9+i] = xrow[288 + ua*7 + i]; xr1[9+i] = xrow[288 + ub*7 + i]; }
    }

    do_group<0>(lane,el4,u0,bvaddr,avaddr,xr0,xr1,w3j,Awhi,Awlo,Abhi,Ablo,
                s_Y[wave], s_zp[wave], s_Bhi[wave], s_Blo[wave], s_len[wave], s_msg[wave]);
    do_group<1>(lane,el4,u0,bvaddr,avaddr,xr0,xr1,w3j,Awhi,Awlo,Abhi,Ablo,
                s_Y[wave], s_zp[wave], s_Bhi[wave], s_Blo[wave], s_len[wave], s_msg[wave]);
    do_group<2>(lane,el4,u0,bvaddr,avaddr,xr0,xr1,w3j,Awhi,Awlo,Abhi,Ablo,
                s_Y[wave], s_zp[wave], s_Bhi[wave], s_Blo[wave], s_len[wave], s_msg[wave]);
    do_group<3>(lane,el4,u0,bvaddr,avaddr,xr0,xr1,w3j,Awhi,Awlo,Abhi,Ablo,
                s_Y[wave], s_zp[wave], s_Bhi[wave], s_Blo[wave], s_len[wave], s_msg[wave]);
    WAVE_SYNC();

    // wave-local coalesced scatter: 4 edges x 512 (R11 actor pattern)
    for (int i = lane; i < 4*FEAT; i += 64) {
        const int elc = i >> 9, m = i & 511;
        atomicAdd(&out[(size_t)s_dst[wave][elc]*FEAT + m], s_msg[wave][i]);
    }
}

extern "C" void kernel_launch(void* const* d_in, const int* in_sizes, int n_in,
                              void* d_out, int out_size, void* d_ws, size_t ws_size,
                              hipStream_t stream) {
    const float* nf   = (const float*)d_in[0];
    const int*   eidx = (const int*)  d_in[1];
    const float* ev   = (const float*)d_in[2];
    const float* ww   = (const float*)d_in[3];
    const float* wb   = (const float*)d_in[4];
    float* out = (float*)d_out;

    float* w3j = (float*)d_ws;                                   // 7500 B
    unsigned short* Awhi = (unsigned short*)((char*)d_ws + 16384);
    unsigned short* Awlo = Awhi + N_PATHS*1024;
    unsigned short* Abhi = Awlo + N_PATHS*1024;
    unsigned short* Ablo = Abhi + N_PATHS*1024;                  // ends at 204800 B

    w3j_setup_kernel<<<N_PATHS + ZERO_BLOCKS, 512, 0, stream>>>(
        ww, wb, w3j, Awhi, Awlo, Abhi, Ablo, out);
    edge_kernel<<<N_EDGES/8, BLK, 0, stream>>>(nf, eidx, ev, w3j, Awhi, Awlo, Abhi, Ablo, out);
}

// Round 13
// 120.374 us; speedup vs baseline: 1.4420x; 1.0054x over previous
//
#include <hip/hip_runtime.h>
#include <math.h>

#define N_PATHS 23
#define HIDDEN  32
#define N_NODES 4096
#define N_EDGES 8192
#define FEAT    512
#define BLK     128   // 2 waves; 4 edges per wave (R11/R20 structure; R22 soft fences)
#define ZERO_BLOCKS 256

// R22: COMPILER-ONLY phase separator. Per-wave DS ops execute in order on the
// LDS pipe (HW-verified: R15 passed with no fences at all), so RAW/WAR through
// wave-local LDS needs no hardware wait; the compiler inserts counted
// lgkmcnt(N) before true data uses. The "memory" clobber pins instruction
// placement exactly as R11's s_waitcnt did — without stalling the wave.
#define WAVE_SYNC() asm volatile("" ::: "memory")

typedef __attribute__((ext_vector_type(8)))  short bf16x8;
typedef __attribute__((ext_vector_type(16))) float f32x16;

// ---- compile-time path metadata (PATHS enumeration: l1 outer, l2, l3) ----
constexpr int cL1[N_PATHS] = {0,0,0,0, 1,1,1,1,1,1, 2,2,2,2,2,2,2, 3,3,3,3,3,3};
constexpr int cL2[N_PATHS] = {0,1,2,3, 0,1,1,2,2,3, 0,1,1,2,2,3,3, 0,1,2,2,3,3};
constexpr int cCOFF[N_PATHS]= {0,1,10,35,84,93,102,147,192,297,402,427,472,577,602,727,832,1077,1126,1231,1336,1581,1630};
constexpr int cL3P[N_PATHS] = {0,5,13,21, 1,4,7,11,15,19, 2,6,9,10,14,18,22, 3,8,12,16,17,20};
constexpr int cL3S[5] = {0,4,10,17,23};
constexpr int cOFF3[4] = {0,32,128,288};
__device__ const int CNT_L3[4] = {4,6,7,6};
__device__ const int D_L3[N_PATHS] = {0,1,2,3, 1,0,2,1,3,2, 2,1,3,0,2,1,3, 3,2,1,3,0,2};

// per-edge z offset of path slot pi within its group's batched z buffer
constexpr int zOff(int G, int pi) {
    int off = 0;
    for (int q = cL3S[G]; q < pi; ++q) off += (2*cL1[cL3P[q]]+1)*(2*G+1);
    return off;
}
// max per-edge z total over groups: G3 = 196 -> 4*196 = 784 floats

constexpr int grpN (int G)        { return cL3S[G+1] - cL3S[G]; }
constexpr int pSlot(int G, int i) { return cL3P[cL3S[G] + i]; }
constexpr int zO   (int G, int i) { return zOff(G, cL3S[G] + i); }
// A-pointer offset and z float offset for slot i of group G (wave-uniform scalars)
constexpr int pOffA(int G, int i) { return pSlot(G,i) * 1024; }
constexpr int zOff4(int G, int i) { return 4 * zO(G,i); }

// ---- 8-point Gauss-Legendre nodes/weights (128-pt rule: exact for degree<=9 SH triple products) ----
__device__ const double GLX8[8] = {
    -0.96028985649753623168, -0.79666647741362673959, -0.52553240991632898582, -0.18343464249564980494,
     0.18343464249564980494,  0.52553240991632898582,  0.79666647741362673959,  0.96028985649753623168};
__device__ const double GLW8[8] = {
     0.10122853629037625915,  0.22238103445337447054,  0.31370664587788728734,  0.36268378337836198297,
     0.36268378337836198297,  0.31370664587788728734,  0.22238103445337447054,  0.10122853629037625915};
// cos/sin(k*pi/8), k=0..15 — exact literals
__device__ const double COSP16[16] = {
  1.0,                     0.92387953251128675613,  0.70710678118654752440,  0.38268343236508977173,
  0.0,                    -0.38268343236508977173, -0.70710678118654752440, -0.92387953251128675613,
 -1.0,                    -0.92387953251128675613, -0.70710678118654752440, -0.38268343236508977173,
  0.0,                     0.38268343236508977173,  0.70710678118654752440,  0.92387953251128675613};
__device__ const double SINP16[16] = {
  0.0,                     0.38268343236508977173,  0.70710678118654752440,  0.92387953251128675613,
  1.0,                     0.92387953251128675613,  0.70710678118654752440,  0.38268343236508977173,
  0.0,                    -0.38268343236508977173, -0.70710678118654752440, -0.92387953251128675613,
 -1.0,                    -0.92387953251128675613, -0.70710678118654752440, -0.38268343236508977173};

__device__ inline void sh_f64(double x, double y, double z, double* Y) {
    const double s3 = 1.7320508075688772935, s5 = 2.2360679774997896964,
                 s7 = 2.6457513110645905905, s15 = 3.8729833462074168852;
    const double c58 = 0.79056941504209483300, c38 = 0.61237243569579452455;
    Y[0] = 1.0;
    Y[1] = s3*x;  Y[2] = s3*y;  Y[3] = s3*z;
    Y[4] = s5*s3*x*z;  Y[5] = s5*s3*x*y;
    Y[6] = s5*(y*y - 0.5*(x*x + z*z));
    Y[7] = s5*s3*y*z;  Y[8] = s5*(s3/2.0)*(z*z - x*x);
    Y[9] = s7*c58*x*(3.0*z*z - x*x);
    Y[10]= s7*s15*x*y*z;
    Y[11]= s7*c38*x*(5.0*y*y - 1.0);
    Y[12]= s7*0.5*y*(5.0*y*y - 3.0);
    Y[13]= s7*c38*z*(5.0*y*y - 1.0);
    Y[14]= s7*(s15/2.0)*y*(z*z - x*x);
    Y[15]= s7*c58*z*(z*z - 3.0*x*x);
}

__device__ inline void sh_f32(float x, float y, float z, float* Y) {
    const float s3 = 1.73205080757f, s5 = 2.23606797750f, s7 = 2.64575131106f, s15 = 3.87298334621f;
    const float c58 = 0.79056941504f, c38 = 0.61237243570f;
    Y[0] = 1.0f;
    Y[1] = s3*x;  Y[2] = s3*y;  Y[3] = s3*z;
    Y[4] = s15*x*z;  Y[5] = s15*x*y;
    Y[6] = s5*(y*y - 0.5f*(x*x + z*z));
    Y[7] = s15*y*z;  Y[8] = s5*(s3*0.5f)*(z*z - x*x);
    Y[9] = s7*c58*x*(3.0f*z*z - x*x);
    Y[10]= s7*s15*x*y*z;
    Y[11]= s7*c38*x*(5.0f*y*y - 1.0f);
    Y[12]= s7*0.5f*y*(5.0f*y*y - 3.0f);
    Y[13]= s7*c38*z*(5.0f*y*y - 1.0f);
    Y[14]= s7*(s15*0.5f)*y*(z*z - x*x);
    Y[15]= s7*c58*z*(z*z - 3.0f*x*x);
}

__device__ inline unsigned short bf16rne(float x) {
    unsigned int u = __float_as_uint(x);
    unsigned int r = (u + 0x7FFFu + ((u >> 16) & 1u)) >> 16;
    return (unsigned short)r;
}
__device__ inline float bf16f(unsigned short h) {
    return __uint_as_float(((unsigned int)h) << 16);
}

// ---- setup: W3J tables (128-pt quadrature) + weight transpose + output zeroing ----
__global__ __launch_bounds__(512) void w3j_setup_kernel(
    const float* __restrict__ ww, const float* __restrict__ wb,
    float* __restrict__ g_w3j,
    unsigned short* __restrict__ Awhi, unsigned short* __restrict__ Awlo,
    unsigned short* __restrict__ Abhi, unsigned short* __restrict__ Ablo,
    float* __restrict__ out) {
    const int t = threadIdx.x;

    if (blockIdx.x >= N_PATHS) {   // zero-blocks
        const int b = blockIdx.x - N_PATHS;
        float4* o4 = (float4*)(out + (size_t)b * (N_NODES*FEAT/ZERO_BLOCKS));
#pragma unroll
        for (int r = 0; r < 4; ++r)
            o4[t + 512*r] = make_float4(0.f,0.f,0.f,0.f);
        return;
    }

    __shared__ float s_Yq[128][17];
    __shared__ float s_wq[128];
    __shared__ float s_part[256];
    __shared__ float red[256];
    __shared__ float s_scale;

    const int p = blockIdx.x;
    const int l1 = cL1[p], l2 = cL2[p];
    const int l3 = D_L3[p];
    const int d2 = 2*l2+1, d3 = 2*l3+1;
    const int csize = (2*l1+1)*d2*d3;
    const double step = 2.0*3.14159265358979323846/16.0;

    // weight transpose to A-layout [p][w][u], bf16 hi/lo split
#pragma unroll
    for (int r = 0; r < 2; ++r) {
        const int idx = t + 512*r;
        const int w = idx >> 5, u = idx & 31;
        const float vw = ww[p*1024 + u*32 + w];
        const float vb = wb[p*1024 + u*32 + w];
        const unsigned short hw = bf16rne(vw);
        const unsigned short hb = bf16rne(vb);
        const int o = p*1024 + w*32 + u;
        Awhi[o] = hw;  Awlo[o] = bf16rne(vw - bf16f(hw));
        Abhi[o] = hb;  Ablo[o] = bf16rne(vb - bf16f(hb));
    }

    // phase A: one quadrature point per thread (first 128 threads)
    if (t < 128) {
        const int iu = t >> 4, ip = t & 15;
        const double u = GLX8[iu];
        const double st = sqrt(fmax(1.0 - u*u, 0.0));
        double Y[16];
        sh_f64(st*COSP16[ip], st*SINP16[ip], u, Y);
#pragma unroll
        for (int i = 0; i < 16; ++i) s_Yq[t][i] = (float)Y[i];
        s_wq[t] = (float)(GLW8[iu] * step);
    }
    __syncthreads();

    // phase B: 4 threads/entry, 32 interleaved points each, shuffle-reduce
    const int entry0 = t >> 2, sub = t & 3;
#pragma unroll
    for (int pass = 0; pass < 2; ++pass) {
        const int entry = entry0 + pass*128;
        float acc = 0.f;
        if (entry < csize) {
            const int i = entry/(d2*d3); const int r = entry - i*(d2*d3);
            const int j = r/d3; const int k = r - j*d3;
            const int ai = l1*l1+i, bi = l2*l2+j, ci = l3*l3+k;
#pragma unroll 4
            for (int it = 0; it < 32; ++it) {
                const int q = it*4 + sub;
                acc = fmaf(s_wq[q] * s_Yq[q][ai] * s_Yq[q][bi], s_Yq[q][ci], acc);
            }
        }
        acc += __shfl_xor(acc, 1);
        acc += __shfl_xor(acc, 2);
        if (sub == 0 && entry < csize) s_part[entry] = acc;
    }
    __syncthreads();

    if (t < 256) { const float v = (t < csize) ? s_part[t] : 0.f; red[t] = v*v; }
    __syncthreads();
    for (int s = 128; s > 0; s >>= 1) {
        if (t < s) red[t] += red[t+s];
        __syncthreads();
    }
    if (t == 0) {
        const float pw = sqrtf((float)(2*l3+1) / ((float)CNT_L3[l3] * (float)HIDDEN));
        s_scale = pw / sqrtf(red[0]);
    }
    __syncthreads();
    if (t < csize) g_w3j[cCOFF[p] + t] = s_part[t] * s_scale;
}

// ---- batched z for one path (no sync): z[el][i][k] into group z buffer ----
template<int G, int P, int ZOFF>
__device__ __forceinline__ void do_zpath(
    int lane, const float* __restrict__ w3j, const float* sY, float* sz)
{
    constexpr int l1 = cL1[P], l2 = cL2[P];
    constexpr int d1 = 2*l1+1, d2 = 2*l2+1, d3 = 2*G+1;
    constexpr int zc = d1*d3;
#pragma unroll
    for (int base = 0; base < 4*zc; base += 64) {
        const int idx = base + lane;
        if (idx < 4*zc) {
            const int elz = idx / zc;          // const-div
            const int r = idx - elz*zc;
            const int i = r / d3, k = r - i*d3;
            const float* Cp = w3j + cCOFF[P] + i*(d2*d3) + k;
            const float* Yp = sY + elz*16 + l2*l2;
            float acc = 0.f;
#pragma unroll
            for (int j = 0; j < d2; ++j) acc = fmaf(Yp[j], Cp[j*d3], acc);
            sz[4*ZOFF + elz*zc + r] = acc;
        }
    }
}

// ---- ONE path body, shapes compile-time, base offsets runtime (R20 dedup unit) ----
// Schedule = R11; fences are compiler-only (R22): per-wave in-order DS handles the
// stage-write -> B-read RAW and the B-read -> next-stage WAR without HW drains.
template<int G, int D1>
__device__ __forceinline__ void path_body(
    int Poff, int zoff4,                       // wave-uniform: A table offset, z float offset
    int el4, int u0, int bvaddr, int avaddr,
    const float (&xr0)[16], const float (&xr1)[16],
    const unsigned short* __restrict__ Awhi, const unsigned short* __restrict__ Awlo,
    const unsigned short* __restrict__ Abhi, const unsigned short* __restrict__ Ablo,
    const float* sz,
    unsigned short* sbh, unsigned short* sbl,
    f32x16 &Cw, f32x16 &Cb)
{
    constexpr int d3 = 2*G+1;
    constexpr int zc = D1*d3;
    constexpr int l1 = (D1-1)/2;
    constexpr int xo = l1*l1;

    // A-operand loads (global/L2) BEFORE the tmp VALU block hides their latency
    bf16x8 awh[2], awl[2], abh[2], abl[2];
#pragma unroll
    for (int kc = 0; kc < 2; ++kc) {
        awh[kc] = *(const bf16x8*)(Awhi + Poff + avaddr + kc*16);
        awl[kc] = *(const bf16x8*)(Awlo + Poff + avaddr + kc*16);
        abh[kc] = *(const bf16x8*)(Abhi + Poff + avaddr + kc*16);
        abl[kc] = *(const bf16x8*)(Ablo + Poff + avaddr + kc*16);
    }

    // tmp[u][k] = sum_i x[u,i]*z[i,k] for u=2u0,2u0+1; chop-split bf16; packed u32 stores
    {
        const float* zr = sz + zoff4 + el4*zc;
        unsigned short* bh = sbh + (el4*d3)*40 + 2*u0;
        unsigned short* bl = sbl + (el4*d3)*40 + 2*u0;
#pragma unroll
        for (int k = 0; k < d3; ++k) {
            float t0 = 0.f, t1 = 0.f;
#pragma unroll
            for (int i = 0; i < D1; ++i) {
                const float zz = zr[i*d3 + k];
                t0 = fmaf(xr0[xo+i], zz, t0);
                t1 = fmaf(xr1[xo+i], zz, t1);
            }
            const unsigned int b0 = __float_as_uint(t0);
            const unsigned int b1 = __float_as_uint(t1);
            const float l0 = t0 - __uint_as_float(b0 & 0xFFFF0000u);
            const float l1f = t1 - __uint_as_float(b1 & 0xFFFF0000u);
            *(unsigned int*)(bh + k*40) = (b0 >> 16) | (b1 & 0xFFFF0000u);
            *(unsigned int*)(bl + k*40) = (__float_as_uint(l0) >> 16) | (__float_as_uint(l1f) & 0xFFFF0000u);
        }
    }
    WAVE_SYNC();   // placement fence only: stores stay before reads (in-order DS does the rest)

    // B loads + 12 MFMA (2 K-chunks x 3-pass hi/lo x {w,b}), interleaved dual chains
    __builtin_amdgcn_s_setprio(1);
#pragma unroll
    for (int kc = 0; kc < 2; ++kc) {
        const bf16x8 bh = *(const bf16x8*)(sbh + bvaddr + kc*16);
        const bf16x8 bl = *(const bf16x8*)(sbl + bvaddr + kc*16);
        Cw = __builtin_amdgcn_mfma_f32_32x32x16_bf16(awh[kc], bh, Cw, 0, 0, 0);
        Cb = __builtin_amdgcn_mfma_f32_32x32x16_bf16(abh[kc], bh, Cb, 0, 0, 0);
        Cw = __builtin_amdgcn_mfma_f32_32x32x16_bf16(awh[kc], bl, Cw, 0, 0, 0);
        Cb = __builtin_amdgcn_mfma_f32_32x32x16_bf16(abh[kc], bl, Cb, 0, 0, 0);
        Cw = __builtin_amdgcn_mfma_f32_32x32x16_bf16(awl[kc], bh, Cw, 0, 0, 0);
        Cb = __builtin_amdgcn_mfma_f32_32x32x16_bf16(abl[kc], bh, Cb, 0, 0, 0);
    }
    __builtin_amdgcn_s_setprio(0);
    WAVE_SYNC();   // placement fence: next path's stage stores ordered after these reads
}

// ---- R20: two same-shape paths share ONE code body (rolled 2-trip loop) ----
template<int G, int D1>
__device__ __forceinline__ void run_pair(
    int P0, int Z0, int P1, int Z1,
    int el4, int u0, int bvaddr, int avaddr,
    const float (&xr0)[16], const float (&xr1)[16],
    const unsigned short* __restrict__ Awhi, const unsigned short* __restrict__ Awlo,
    const unsigned short* __restrict__ Abhi, const unsigned short* __restrict__ Ablo,
    const float* sz,
    unsigned short* sbh, unsigned short* sbl,
    f32x16 &Cw, f32x16 &Cb)
{
#pragma unroll 1
    for (int r = 0; r < 2; ++r) {
        path_body<G, D1>(r ? P1 : P0, r ? Z1 : Z0,
                         el4, u0, bvaddr, avaddr, xr0, xr1,
                         Awhi, Awlo, Abhi, Ablo, sz, sbh, sbl, Cw, Cb);
    }
}

// ---- one l3 group: batched z, then deduped per-path tmp+MFMA; epilogue into s_msg ----
template<int G>
__device__ __forceinline__ void do_group(
    int lane, int el4, int u0, int bvaddr, int avaddr,
    const float (&xr0)[16], const float (&xr1)[16],
    const float* __restrict__ w3j,
    const unsigned short* __restrict__ Awhi, const unsigned short* __restrict__ Awlo,
    const unsigned short* __restrict__ Abhi, const unsigned short* __restrict__ Ablo,
    const float* sY, float* sz,
    unsigned short* sbh, unsigned short* sbl,
    const float* slen, float* smsg)
{
    constexpr int d3 = 2*G+1;
    constexpr int n = grpN(G);
    f32x16 Cw = (f32x16)(0.f), Cb = (f32x16)(0.f);

    // batched z: all paths of the group (z writes ordered before z reads by in-order DS)
    do_zpath<G, pSlot(G,0), zO(G,0)>(lane, w3j, sY, sz);
    do_zpath<G, pSlot(G,1), zO(G,1)>(lane, w3j, sY, sz);
    do_zpath<G, pSlot(G,2), zO(G,2)>(lane, w3j, sY, sz);
    do_zpath<G, pSlot(G,3), zO(G,3)>(lane, w3j, sY, sz);
    if constexpr (n > 4) do_zpath<G, pSlot(G,4), zO(G,4)>(lane, w3j, sY, sz);
    if constexpr (n > 5) do_zpath<G, pSlot(G,5), zO(G,5)>(lane, w3j, sY, sz);
    if constexpr (n > 6) do_zpath<G, pSlot(G,6), zO(G,6)>(lane, w3j, sY, sz);
    WAVE_SYNC();

    // path phase, same path ORDER as R11 (slots ascending) — numerics identical.
    if constexpr (G == 0) {
        path_body<0,1>(pOffA(0,0), zOff4(0,0), el4,u0,bvaddr,avaddr,xr0,xr1,Awhi,Awlo,Abhi,Ablo,sz,sbh,sbl,Cw,Cb);
        path_body<0,3>(pOffA(0,1), zOff4(0,1), el4,u0,bvaddr,avaddr,xr0,xr1,Awhi,Awlo,Abhi,Ablo,sz,sbh,sbl,Cw,Cb);
        path_body<0,5>(pOffA(0,2), zOff4(0,2), el4,u0,bvaddr,avaddr,xr0,xr1,Awhi,Awlo,Abhi,Ablo,sz,sbh,sbl,Cw,Cb);
        path_body<0,7>(pOffA(0,3), zOff4(0,3), el4,u0,bvaddr,avaddr,xr0,xr1,Awhi,Awlo,Abhi,Ablo,sz,sbh,sbl,Cw,Cb);
    } else if constexpr (G == 1) {
        path_body<1,1>(pOffA(1,0), zOff4(1,0), el4,u0,bvaddr,avaddr,xr0,xr1,Awhi,Awlo,Abhi,Ablo,sz,sbh,sbl,Cw,Cb);
        run_pair <1,3>(pOffA(1,1), zOff4(1,1), pOffA(1,2), zOff4(1,2), el4,u0,bvaddr,avaddr,xr0,xr1,Awhi,Awlo,Abhi,Ablo,sz,sbh,sbl,Cw,Cb);
        run_pair <1,5>(pOffA(1,3), zOff4(1,3), pOffA(1,4), zOff4(1,4), el4,u0,bvaddr,avaddr,xr0,xr1,Awhi,Awlo,Abhi,Ablo,sz,sbh,sbl,Cw,Cb);
        path_body<1,7>(pOffA(1,5), zOff4(1,5), el4,u0,bvaddr,avaddr,xr0,xr1,Awhi,Awlo,Abhi,Ablo,sz,sbh,sbl,Cw,Cb);
    } else if constexpr (G == 2) {
        path_body<2,1>(pOffA(2,0), zOff4(2,0), el4,u0,bvaddr,avaddr,xr0,xr1,Awhi,Awlo,Abhi,Ablo,sz,sbh,sbl,Cw,Cb);
        run_pair <2,3>(pOffA(2,1), zOff4(2,1), pOffA(2,2), zOff4(2,2), el4,u0,bvaddr,avaddr,xr0,xr1,Awhi,Awlo,Abhi,Ablo,sz,sbh,sbl,Cw,Cb);
        run_pair <2,5>(pOffA(2,3), zOff4(2,3), pOffA(2,4), zOff4(2,4), el4,u0,bvaddr,avaddr,xr0,xr1,Awhi,Awlo,Abhi,Ablo,sz,sbh,sbl,Cw,Cb);
        run_pair <2,7>(pOffA(2,5), zOff4(2,5), pOffA(2,6), zOff4(2,6), el4,u0,bvaddr,avaddr,xr0,xr1,Awhi,Awlo,Abhi,Ablo,sz,sbh,sbl,Cw,Cb);
    } else {
        path_body<3,1>(pOffA(3,0), zOff4(3,0), el4,u0,bvaddr,avaddr,xr0,xr1,Awhi,Awlo,Abhi,Ablo,sz,sbh,sbl,Cw,Cb);
        path_body<3,3>(pOffA(3,1), zOff4(3,1), el4,u0,bvaddr,avaddr,xr0,xr1,Awhi,Awlo,Abhi,Ablo,sz,sbh,sbl,Cw,Cb);
        run_pair <3,5>(pOffA(3,2), zOff4(3,2), pOffA(3,3), zOff4(3,3), el4,u0,bvaddr,avaddr,xr0,xr1,Awhi,Awlo,Abhi,Ablo,sz,sbh,sbl,Cw,Cb);
        run_pair <3,7>(pOffA(3,4), zOff4(3,4), pOffA(3,5), zOff4(3,5), el4,u0,bvaddr,avaddr,xr0,xr1,Awhi,Awlo,Abhi,Ablo,sz,sbh,sbl,Cw,Cb);
    }

    // epilogue: msg = len*Cw + Cb
    // C/D layout (verified m74/m101): col=lane&31, row=(reg&3)+8*(reg>>2)+4*(lane>>5)
    const int col = lane & 31;
    if (col < 4*d3) {
        const int elc = col / d3, k = col - elc*d3;   // const-div
        const float len = slen[elc];
        float* mp = smsg + elc*FEAT + cOFF3[G] + k;
#pragma unroll
        for (int reg = 0; reg < 16; ++reg) {
            const int w = (reg & 3) + 8*(reg >> 2) + 4*(lane >> 5);
            mp[w*d3] = fmaf(len, Cw[reg], Cb[reg]);
        }
    }
}

// ---- main: 2 waves/block, 4 edges/wave, 32x32x16 MFMA (R20 + R22 soft fences) ----
__global__ __launch_bounds__(BLK) void edge_kernel(
    const float* __restrict__ nf,
    const int*   __restrict__ eidx,
    const float* __restrict__ ev,
    const float* __restrict__ w3j,
    const unsigned short* __restrict__ Awhi,
    const unsigned short* __restrict__ Awlo,
    const unsigned short* __restrict__ Abhi,
    const unsigned short* __restrict__ Ablo,
    float*       __restrict__ out)
{
    __shared__ float s_zp[2][784];       // batched per-group z (max G3: 4*196)
    __shared__ float s_Y[2][64];
    __shared__ float s_len[2][4];
    __shared__ int   s_src[2][4];
    __shared__ int   s_dst[2][4];
    __shared__ __align__(16) unsigned short s_Bhi[2][1280];  // [col(32)][u(32)+pad8]
    __shared__ __align__(16) unsigned short s_Blo[2][1280];
    __shared__ float s_msg[2][4*FEAT];

    const int t    = threadIdx.x;
    const int wave = t >> 6;
    const int lane = t & 63;
    const int el4  = lane >> 4;      // tmp-phase edge (4 per wave)
    const int u0   = lane & 15;      // tmp-phase u-pair index
    const int e0   = blockIdx.x * 8 + wave*4;
    const int bvaddr = (lane & 31)*40 + (lane >> 5)*8;   // B: n=lane&31, k0=(lane>>5)*8
    const int avaddr = (lane & 31)*32 + (lane >> 5)*8;   // A: m=lane&31, k0=(lane>>5)*8

    if (lane < 4) {
        const int e = e0 + lane;
        s_src[wave][lane] = eidx[e];
        s_dst[wave][lane] = eidx[N_EDGES + e];
        const float x = ev[e*3+0], y = ev[e*3+1], z = ev[e*3+2];
        const float len = sqrtf(x*x + y*y + z*z);
        const float lc = fmaxf(len, 1e-8f);
        s_len[wave][lane] = lc;
        float Yl[16];
        sh_f32(x/lc, y/lc, z/lc, Yl);
#pragma unroll
        for (int i = 0; i < 16; ++i) s_Y[wave][lane*16+i] = Yl[i];
    }
    WAVE_SYNC();

    // preload this lane's 2 u-rows of x (u = 2u0, 2u0+1) into registers
    float xr0[16], xr1[16];
    {
        const float* xrow = nf + (size_t)s_src[wave][el4]*FEAT;
        const int ua = 2*u0, ub = 2*u0 + 1;
        xr0[0] = xrow[ua];                 xr1[0] = xrow[ub];
#pragma unroll
        for (int i = 0; i < 3; ++i) { xr0[1+i] = xrow[32 + ua*3 + i];  xr1[1+i] = xrow[32 + ub*3 + i]; }
#pragma unroll
        for (int i = 0; i < 5; ++i) { xr0[4+i] = xrow[128 + ua*5 + i]; xr1[4+i] = xrow[128 + ub*5 + i]; }
#pragma unroll
        for (int i = 0; i < 7; ++i) { xr0[9+i] = xrow[288 + ua*7 + i]; xr1[9+i] = xrow[288 + ub*7 + i]; }
    }

    do_group<0>(lane,el4,u0,bvaddr,avaddr,xr0,xr1,w3j,Awhi,Awlo,Abhi,Ablo,
                s_Y[wave], s_zp[wave], s_Bhi[wave], s_Blo[wave], s_len[wave], s_msg[wave]);
    do_group<1>(lane,el4,u0,bvaddr,avaddr,xr0,xr1,w3j,Awhi,Awlo,Abhi,Ablo,
                s_Y[wave], s_zp[wave], s_Bhi[wave], s_Blo[wave], s_len[wave], s_msg[wave]);
    do_group<2>(lane,el4,u0,bvaddr,avaddr,xr0,xr1,w3j,Awhi,Awlo,Abhi,Ablo,
                s_Y[wave], s_zp[wave], s_Bhi[wave], s_Blo[wave], s_len[wave], s_msg[wave]);
    do_group<3>(lane,el4,u0,bvaddr,avaddr,xr0,xr1,w3j,Awhi,Awlo,Abhi,Ablo,
                s_Y[wave], s_zp[wave], s_Bhi[wave], s_Blo[wave], s_len[wave], s_msg[wave]);
    WAVE_SYNC();

    // wave-local coalesced scatter: 4 edges x 512 (R11 actor pattern)
    for (int i = lane; i < 4*FEAT; i += 64) {
        const int elc = i >> 9, m = i & 511;
        atomicAdd(&out[(size_t)s_dst[wave][elc]*FEAT + m], s_msg[wave][i]);
    }
}

extern "C" void kernel_launch(void* const* d_in, const int* in_sizes, int n_in,
                              void* d_out, int out_size, void* d_ws, size_t ws_size,
                              hipStream_t stream) {
    const float* nf   = (const float*)d_in[0];
    const int*   eidx = (const int*)  d_in[1];
    const float* ev   = (const float*)d_in[2];
    const float* ww   = (const float*)d_in[3];
    const float* wb   = (const float*)d_in[4];
    float* out = (float*)d_out;

    float* w3j = (float*)d_ws;                                   // 7500 B
    unsigned short* Awhi = (unsigned short*)((char*)d_ws + 16384);
    unsigned short* Awlo = Awhi + N_PATHS*1024;
    unsigned short* Abhi = Awlo + N_PATHS*1024;
    unsigned short* Ablo = Abhi + N_PATHS*1024;                  // ends at 204800 B

    w3j_setup_kernel<<<N_PATHS + ZERO_BLOCKS, 512, 0, stream>>>(
        ww, wb, w3j, Awhi, Awlo, Abhi, Ablo, out);
    edge_kernel<<<N_EDGES/8, BLK, 0, stream>>>(nf, eidx, ev, w3j, Awhi, Awlo, Abhi, Ablo, out);
}